// Round 1
// 471.502 us; speedup vs baseline: 1.2407x; 1.2407x over previous
//
#include <hip/hip_runtime.h>
#include <math.h>

#define BB 8
#define NN 20000
#define PP 256
#define SSAMP 32
#define CC 256

typedef unsigned short u16;
typedef unsigned int u32;
typedef __attribute__((ext_vector_type(8))) short short8;
typedef __attribute__((ext_vector_type(4))) float f32x4;

__device__ __forceinline__ float b2f(u16 u) {
    union { u32 i; float f; } x; x.i = ((u32)u) << 16; return x.f;
}
__device__ __forceinline__ u16 f2b(float f) {
    union { float f; u32 i; } x; x.f = f;
    u32 i = x.i;
    i += 0x7fffu + ((i >> 16) & 1u);
    return (u16)(i >> 16);
}
__device__ __forceinline__ float rnd_bf(float f) { return b2f(f2b(f)); }
__device__ __forceinline__ float geluf(float x) {
    return 0.5f * x * (1.0f + erff(x * 0.7071067811865476f));
}
__device__ __forceinline__ float siluf(float x) {
    return x / (1.0f + expf(-x));
}
__device__ __forceinline__ f32x4 fz4() { f32x4 z = {0.f,0.f,0.f,0.f}; return z; }

// dtype-adaptive loads: flag=1 -> f32 input, flag=0 -> bf16 input
__device__ __forceinline__ float ldf(const void* p, size_t i, int f32f) {
    return f32f ? ((const float*)p)[i] : b2f(((const u16*)p)[i]);
}
__device__ __forceinline__ u16 ldw(const void* p, size_t i, int f32f) {
    return f32f ? f2b(((const float*)p)[i]) : ((const u16*)p)[i];
}

// ---------------- dtype detection ----------------
__global__ void k_detect(const u16* __restrict__ xyzU, int* __restrict__ flagW) {
    int lane = threadIdx.x;            // 64 threads
    u16 u = xyzU[(size_t)lane * 7496];
    int e = (u >> 7) & 0xFF;
    bool inR = (e >= 0x70) && (e <= 0x85);
    unsigned long long m = __ballot(inR);
    if (lane == 0) *flagW = (__popcll(m) < 48) ? 1 : 0;
}

// ---------------- repack weights -> bf16 blobs, biases -> f32 ----------------
__global__ __launch_bounds__(256) void k_repack(const int* __restrict__ flagp,
        const void* mw0, const void* mb0, const void* mw1, const void* mb1,
        const void* mw2, const void* mb2,
        const void* lw0, const void* lb0, const void* lw1, const void* lb1,
        const void* lw2, const void* lb2,
        u16* __restrict__ W0p, u16* __restrict__ W1p, u16* __restrict__ W2p,
        u16* __restrict__ L0p, u16* __restrict__ L1p, u16* __restrict__ L2p,
        float* __restrict__ biasF) {
    int f32f = *flagp;
    int i = blockIdx.x * 256 + threadIdx.x;
    if (i < 36864) {
        int o = i / 288, c = i % 288;
        u16 v = 0;
        if (c < 256) v = ldw(mw0, o * 259 + 3 + c, f32f);
        else if (c < 259) v = ldw(mw0, o * 259 + (c - 256), f32f);
        W0p[i] = v;
    } else if (i < 53248) {
        W1p[i - 36864] = ldw(mw1, i - 36864, f32f);
    } else if (i < 69632) {
        W2p[i - 53248] = ldw(mw2, i - 53248, f32f);
    } else if (i < 110592) {
        int j = i - 69632;
        int o = j / 160, c = j % 160;
        L0p[j] = (c < 146) ? ldw(lw0, o * 146 + c, f32f) : (u16)0;
    } else if (i < 176128) {
        L1p[i - 110592] = ldw(lw1, i - 110592, f32f);
    } else if (i < 241664) {
        L2p[i - 176128] = ldw(lw2, i - 176128, f32f);
    } else if (i < 242816) {
        int j = i - 241664;
        float v;
        if (j < 128) v = ldf(mb0, j, f32f);
        else if (j < 256) v = ldf(mb1, j - 128, f32f);
        else if (j < 384) v = ldf(mb2, j - 256, f32f);
        else if (j < 640) v = ldf(lb0, j - 384, f32f);
        else if (j < 896) v = ldf(lb1, j - 640, f32f);
        else v = ldf(lb2, j - 896, f32f);
        biasF[j] = v;
    }
}

// ---------------- transpose features [B,C,N] -> bf16 [.,N,C] ----------------
// b0: source batch offset; dst batch index is blockIdx.z (tier B uses z=1)
__global__ __launch_bounds__(256) void k_transpose(const int* __restrict__ flagp,
                                                   const void* __restrict__ feat,
                                                   u16* __restrict__ featT, int b0) {
    __shared__ u16 tile[64][66];
    int f32f = *flagp;
    int bz = blockIdx.z, c0 = blockIdx.y * 64, n0 = blockIdx.x * 64;
    int b = b0 + bz;
    int tx = threadIdx.x, ty = threadIdx.y;
    const size_t fb = (size_t)b * CC * NN;
    for (int i = 0; i < 16; i++) {
        int cl = ty * 16 + i;
        int n = n0 + tx;
        if (n < NN) tile[cl][tx] = ldw(feat, fb + (size_t)(c0 + cl) * NN + n, f32f);
    }
    __syncthreads();
    const size_t tb = (size_t)bz * NN * CC;
    for (int i = 0; i < 16; i++) {
        int nl = ty * 16 + i;
        int n = n0 + nl;
        if (n < NN) featT[tb + (size_t)n * CC + c0 + tx] = tile[tx][nl];
    }
}

// ---------------- time-MLP layer: wave-per-row GEMV, all 8 batches per wave ----
// ACT: 0=none 1=gelu 2=silu ; SRC: 0=sinusoid128(ts) 1=sinusoid256(ts) 2=global f32 [8][K]
template<int ACT, int SRC>
__global__ __launch_bounds__(256) void k_lin(const int* __restrict__ flagp,
        const void* __restrict__ xin, const void* __restrict__ W,
        const void* __restrict__ bias, float* __restrict__ out, int K, int O) {
    __shared__ float xs[8 * 1024];
    int f32f = *flagp;
    int tid = threadIdx.x;
    if (SRC == 2) {
        const float* X = (const float*)xin;
        for (int i = tid; i < 8 * K; i += 256) xs[i] = X[i];
    } else {
        const int half = (SRC == 0) ? 64 : 128;
        const int dim = half * 2;
        const float cst = (SRC == 0) ? (logf(10000.f) / 63.f) : (logf(10000.f) / 127.f);
        for (int i = tid; i < 8 * dim; i += 256) {
            int b = i / dim, j = i % dim;
            float t = ldf(xin, b, f32f);
            int jj = (j < half) ? j : (j - half);
            float e = t * expf(-(float)jj * cst);
            xs[i] = (j < half) ? sinf(e) : cosf(e);
        }
    }
    __syncthreads();
    int lane = tid & 63, wv = tid >> 6;
    int r = blockIdx.x * 4 + wv;
    if (r >= O) return;
    float acc[8] = {0.f, 0.f, 0.f, 0.f, 0.f, 0.f, 0.f, 0.f};
    for (int k = lane; k < K; k += 64) {
        float wval = ldf(W, (size_t)r * K + k, f32f);
        #pragma unroll
        for (int b = 0; b < 8; b++) acc[b] += wval * xs[b * K + k];
    }
    #pragma unroll
    for (int b = 0; b < 8; b++) {
        acc[b] += __shfl_xor(acc[b], 1);
        acc[b] += __shfl_xor(acc[b], 2);
        acc[b] += __shfl_xor(acc[b], 4);
        acc[b] += __shfl_xor(acc[b], 8);
        acc[b] += __shfl_xor(acc[b], 16);
        acc[b] += __shfl_xor(acc[b], 32);
    }
    if (lane == 0) {
        float bv = ldf(bias, r, f32f);
        #pragma unroll
        for (int b = 0; b < 8; b++) {
            float v = acc[b] + bv;
            if (ACT == 1) v = geluf(v);
            else if (ACT == 2) v = siluf(v);
            out[b * O + r] = v;
        }
    }
}

// ---------------- sampler: one BLOCK (4 waves) per proposal ----------------
// 1024 points per iteration: each wave scans 4x64 with all loads hoisted
// (MLP-style latency amortization), cross-wave LDS prefix preserves the exact
// "first SSAMP in ascending index order" stable-sort semantics.
__global__ __launch_bounds__(256) void k_sample(const int* __restrict__ flagp,
        const void* __restrict__ xyz,
        const void* __restrict__ bsize, const int* __restrict__ inds,
        int* __restrict__ sidx, float* __restrict__ cenW,
        float* __restrict__ outXyz, float* __restrict__ outInds) {
    __shared__ int sBuf[SSAMP];
    __shared__ int wcnt[4];
    int f32f = *flagp;
    int tid = threadIdx.x;
    int lane = tid & 63, w = tid >> 6;
    int pg = blockIdx.x;
    int b = pg >> 8;
    int ind = inds[pg];
    ind = ind < 0 ? 0 : (ind >= NN ? NN - 1 : ind);
    if (tid < SSAMP) sBuf[tid] = 0;
    size_t xb = (size_t)b * NN * 3;
    float cx = ldf(xyz, xb + (size_t)ind * 3 + 0, f32f);
    float cy = ldf(xyz, xb + (size_t)ind * 3 + 1, f32f);
    float cz = ldf(xyz, xb + (size_t)ind * 3 + 2, f32f);
    float hx = 0.5f * ldf(bsize, pg * 3 + 0, f32f);
    float hy = 0.5f * ldf(bsize, pg * 3 + 1, f32f);
    float hz = 0.5f * ldf(bsize, pg * 3 + 2, f32f);
    int cnt = 0;
    const unsigned long long lmask = (1ull << lane) - 1ull;
    for (int base = 0; base < NN; base += 1024) {
        int nb = base + w * 256 + lane;
        int nn[4];
        float px[4], py[4], pz[4];
        // issue all 12 loads before any use -> memory-level parallelism
        #pragma unroll
        for (int u = 0; u < 4; u++) {
            int n = nb + u * 64;
            nn[u] = n;
            int nc = n < NN ? n : NN - 1;
            size_t a = xb + (size_t)nc * 3;
            px[u] = ldf(xyz, a, f32f);
            py[u] = ldf(xyz, a + 1, f32f);
            pz[u] = ldf(xyz, a + 2, f32f);
        }
        bool isin[4];
        unsigned long long m[4];
        int pc[4];
        int tw = 0;
        #pragma unroll
        for (int u = 0; u < 4; u++) {
            bool in_ = (nn[u] < NN) &&
                       (fabsf(px[u] - cx) <= hx) &&
                       (fabsf(py[u] - cy) <= hy) &&
                       (fabsf(pz[u] - cz) <= hz);
            isin[u] = in_;
            m[u] = __ballot(in_);
            pc[u] = (int)__popcll(m[u]);
            tw += pc[u];
        }
        if (lane == 0) wcnt[w] = tw;
        __syncthreads();
        int w0 = wcnt[0], w1 = wcnt[1], w2 = wcnt[2], w3 = wcnt[3];
        int total = w0 + w1 + w2 + w3;
        int prior = cnt;
        if (w >= 1) prior += w0;
        if (w >= 2) prior += w1;
        if (w >= 3) prior += w2;
        #pragma unroll
        for (int u = 0; u < 4; u++) {
            int pos = prior + (int)__popcll(m[u] & lmask);
            if (isin[u] && pos < SSAMP) sBuf[pos] = nn[u];
            prior += pc[u];
        }
        __syncthreads();          // order sBuf writes before exit-reads / next wcnt write
        cnt += total;             // uniform across block -> uniform break
        if (cnt >= SSAMP) break;
    }
    int ccap = cnt < SSAMP ? cnt : SSAMP;
    if (ccap < 1) ccap = 1;
    if (tid < SSAMP) sidx[pg * SSAMP + tid] = sBuf[tid % ccap];
    if (tid < 3) {
        float cv = tid == 0 ? cx : (tid == 1 ? cy : cz);
        outXyz[pg * 3 + tid] = cv;
        cenW[pg * 3 + tid] = cv;
    }
    if (tid == 0) outInds[pg] = rnd_bf((float)ind);
}

// ---------------- gather + 3-layer MFMA MLP + maxpool + fused FiLM ----------------
// tier: 2 = full featT [8*NN,C]; 1 = single-batch featB [NN,C]; 0 = scalar gather
__global__ __launch_bounds__(256) void k_mlp1(const int* __restrict__ flagp,
        const u16* __restrict__ featT, const void* __restrict__ feat,
        int blockOff, int tier,
        const void* __restrict__ xyz, const int* __restrict__ sidx,
        const float* __restrict__ cenW, const float* __restrict__ ssW,
        const u16* __restrict__ W0p, const u16* __restrict__ W1p,
        const u16* __restrict__ W2p, const float* __restrict__ biasF,
        u16* __restrict__ nfB, float* __restrict__ outNF) {
    __shared__ u16 gA[64 * 296];
    __shared__ u16 h1s[64 * 136];
    __shared__ int nrowS[64];
    __shared__ float centS[8];
    int f32f = *flagp;
    int tid = threadIdx.x;
    int pbase = (blockIdx.x + blockOff) * 2;
    int b = pbase >> 8;
    if (tid < 64) {
        int n = sidx[pbase * SSAMP + tid];
        nrowS[tid] = n < 0 ? 0 : (n >= NN ? NN - 1 : n);
    }
    if (tid < 6) centS[tid] = cenW[pbase * 3 + tid];
    for (int e = tid; e < 64 * 32; e += 256) {
        int row = e >> 5, c2 = e & 31;
        if (c2 >= 8 && c2 < 28)
            *(u32*)&gA[row * 296 + 256 + (c2 - 8) * 2] = 0u;
    }
    __syncthreads();
    if (tier >= 1) {
        size_t rowBase = (tier == 2) ? ((size_t)b * NN) : 0;
        for (int e = tid; e < 64 * 32; e += 256) {
            int row = e >> 5, seg = e & 31;
            int n = nrowS[row];
            uint4 v = *(const uint4*)(featT + (rowBase + n) * CC + seg * 8);
            *(uint4*)&gA[row * 296 + seg * 8] = v;
        }
    } else {
        int row = tid & 63;
        int n = nrowS[row];
        const size_t fb = (size_t)b * CC * NN;
        int cbase = tid >> 6;
        for (int it = 0; it < 64; it++) {
            int cch = it * 4 + cbase;
            gA[row * 296 + cch] = ldw(feat, fb + (size_t)cch * NN + n, f32f);
        }
    }
    if (tid < 64) {
        int row = tid, q = row >> 5;
        int n = nrowS[row];
        size_t a = ((size_t)b * NN + n) * 3;
        for (int d = 0; d < 3; d++) {
            float gv = ldf(xyz, a + d, f32f) - centS[q * 3 + d];
            gA[row * 296 + 256 + d] = f2b(gv);
        }
    }
    __syncthreads();

    int lane = tid & 63, w = tid >> 6;
    int c15 = lane & 15, kq = lane >> 4;
    f32x4 acc[4][2];

    // ---- layer 1: K=288 ----
    for (int mt = 0; mt < 4; mt++) for (int j = 0; j < 2; j++) acc[mt][j] = fz4();
    for (int ks = 0; ks < 9; ks++) {
        int k0 = ks * 32 + kq * 8;
        short8 af[4];
        for (int mt = 0; mt < 4; mt++)
            af[mt] = *(const short8*)&gA[(mt * 16 + c15) * 296 + k0];
        for (int j = 0; j < 2; j++) {
            int col = w * 32 + j * 16 + c15;
            short8 bf = *(const short8*)(W0p + col * 288 + k0);
            for (int mt = 0; mt < 4; mt++)
                acc[mt][j] = __builtin_amdgcn_mfma_f32_16x16x32_bf16(af[mt], bf, acc[mt][j], 0, 0, 0);
        }
    }
    for (int j = 0; j < 2; j++) {
        int col = w * 32 + j * 16 + c15;
        float bias = biasF[col];
        for (int mt = 0; mt < 4; mt++)
            for (int r = 0; r < 4; r++) {
                float v = acc[mt][j][r] + bias;
                v = v > 0.f ? v : 0.f;
                h1s[(mt * 16 + kq * 4 + r) * 136 + col] = f2b(v);
            }
    }
    __syncthreads();

    // ---- layer 2: K=128, h2 aliases gA ----
    u16* h2s = gA;
    for (int mt = 0; mt < 4; mt++) for (int j = 0; j < 2; j++) acc[mt][j] = fz4();
    for (int ks = 0; ks < 4; ks++) {
        int k0 = ks * 32 + kq * 8;
        short8 af[4];
        for (int mt = 0; mt < 4; mt++)
            af[mt] = *(const short8*)&h1s[(mt * 16 + c15) * 136 + k0];
        for (int j = 0; j < 2; j++) {
            int col = w * 32 + j * 16 + c15;
            short8 bf = *(const short8*)(W1p + col * 128 + k0);
            for (int mt = 0; mt < 4; mt++)
                acc[mt][j] = __builtin_amdgcn_mfma_f32_16x16x32_bf16(af[mt], bf, acc[mt][j], 0, 0, 0);
        }
    }
    __syncthreads();
    for (int j = 0; j < 2; j++) {
        int col = w * 32 + j * 16 + c15;
        float bias = biasF[128 + col];
        for (int mt = 0; mt < 4; mt++)
            for (int r = 0; r < 4; r++) {
                float v = acc[mt][j][r] + bias;
                v = v > 0.f ? v : 0.f;
                h2s[(mt * 16 + kq * 4 + r) * 136 + col] = f2b(v);
            }
    }
    __syncthreads();

    // ---- layer 3: K=128 + maxpool + fused FiLM ----
    for (int mt = 0; mt < 4; mt++) for (int j = 0; j < 2; j++) acc[mt][j] = fz4();
    for (int ks = 0; ks < 4; ks++) {
        int k0 = ks * 32 + kq * 8;
        short8 af[4];
        for (int mt = 0; mt < 4; mt++)
            af[mt] = *(const short8*)&h2s[(mt * 16 + c15) * 136 + k0];
        for (int j = 0; j < 2; j++) {
            int col = w * 32 + j * 16 + c15;
            short8 bf = *(const short8*)(W2p + col * 128 + k0);
            for (int mt = 0; mt < 4; mt++)
                acc[mt][j] = __builtin_amdgcn_mfma_f32_16x16x32_bf16(af[mt], bf, acc[mt][j], 0, 0, 0);
        }
    }
    int pA = pbase & 255, pB = (pbase + 1) & 255;
    float scA = ssW[b * 256 + (pA & 127)] + 1.f, shA = ssW[b * 256 + 128 + (pA & 127)];
    float scB = ssW[b * 256 + (pB & 127)] + 1.f, shB = ssW[b * 256 + 128 + (pB & 127)];
    for (int j = 0; j < 2; j++) {
        int col = w * 32 + j * 16 + c15;
        float bias = biasF[256 + col];
        float mA = 0.f, mB = 0.f;
        for (int mt = 0; mt < 2; mt++)
            for (int r = 0; r < 4; r++) {
                float v = acc[mt][j][r] + bias; v = v > 0.f ? v : 0.f;
                mA = fmaxf(mA, v);
            }
        for (int mt = 2; mt < 4; mt++)
            for (int r = 0; r < 4; r++) {
                float v = acc[mt][j][r] + bias; v = v > 0.f ? v : 0.f;
                mB = fmaxf(mB, v);
            }
        mA = fmaxf(mA, __shfl_xor(mA, 16)); mA = fmaxf(mA, __shfl_xor(mA, 32));
        mB = fmaxf(mB, __shfl_xor(mB, 16)); mB = fmaxf(mB, __shfl_xor(mB, 32));
        if (lane < 16) {
            nfB[(size_t)(pbase + 0) * 128 + col] = f2b(mA);
            nfB[(size_t)(pbase + 1) * 128 + col] = f2b(mB);
            outNF[((size_t)b * 128 + col) * 256 + pA] = mA * scA + shA;
            outNF[((size_t)b * 128 + col) * 256 + pB] = mB * scB + shB;
        }
    }
}

// ---------------- label MFMA MLP + fused FiLM: 16 proposals/block ----------------
__global__ __launch_bounds__(256) void k_label(const int* __restrict__ flagp,
        const void* __restrict__ blabel,
        const u16* __restrict__ nfB, const u16* __restrict__ L0p,
        const u16* __restrict__ L1p, const u16* __restrict__ L2p,
        const float* __restrict__ biasF, const float* __restrict__ sslW,
        float* __restrict__ outLF) {
    __shared__ u16 liS[16 * 168];
    __shared__ u16 h1L[16 * 264];
    __shared__ u16 h2L[16 * 264];
    int f32f = *flagp;
    int tid = threadIdx.x;
    int pbase = blockIdx.x * 16;
    for (int e = tid; e < 16 * 160; e += 256) {
        int row = e / 160, c = e % 160;
        int pg = pbase + row;
        u16 v = 0;
        if (c < 18) v = ldw(blabel, pg * 18 + c, f32f);
        else if (c < 146) v = nfB[(size_t)pg * 128 + (c - 18)];
        liS[row * 168 + c] = v;
    }
    __syncthreads();
    int lane = tid & 63, w = tid >> 6;
    int c15 = lane & 15, kq = lane >> 4;
    f32x4 acc[4];

    // layer 1: K=160
    for (int j = 0; j < 4; j++) acc[j] = fz4();
    for (int ks = 0; ks < 5; ks++) {
        int k0 = ks * 32 + kq * 8;
        short8 af = *(const short8*)&liS[c15 * 168 + k0];
        for (int j = 0; j < 4; j++) {
            int col = w * 64 + j * 16 + c15;
            short8 bf = *(const short8*)(L0p + col * 160 + k0);
            acc[j] = __builtin_amdgcn_mfma_f32_16x16x32_bf16(af, bf, acc[j], 0, 0, 0);
        }
    }
    for (int j = 0; j < 4; j++) {
        int col = w * 64 + j * 16 + c15;
        float bias = biasF[384 + col];
        for (int r = 0; r < 4; r++) {
            float v = acc[j][r] + bias; v = v > 0.f ? v : 0.f;
            h1L[(kq * 4 + r) * 264 + col] = f2b(v);
        }
    }
    __syncthreads();

    // layer 2: K=256
    for (int j = 0; j < 4; j++) acc[j] = fz4();
    for (int ks = 0; ks < 8; ks++) {
        int k0 = ks * 32 + kq * 8;
        short8 af = *(const short8*)&h1L[c15 * 264 + k0];
        for (int j = 0; j < 4; j++) {
            int col = w * 64 + j * 16 + c15;
            short8 bf = *(const short8*)(L1p + col * 256 + k0);
            acc[j] = __builtin_amdgcn_mfma_f32_16x16x32_bf16(af, bf, acc[j], 0, 0, 0);
        }
    }
    for (int j = 0; j < 4; j++) {
        int col = w * 64 + j * 16 + c15;
        float bias = biasF[640 + col];
        for (int r = 0; r < 4; r++) {
            float v = acc[j][r] + bias; v = v > 0.f ? v : 0.f;
            h2L[(kq * 4 + r) * 264 + col] = f2b(v);
        }
    }
    __syncthreads();

    // layer 3: K=256 + fused FiLM -> outLF (f32)
    for (int j = 0; j < 4; j++) acc[j] = fz4();
    for (int ks = 0; ks < 8; ks++) {
        int k0 = ks * 32 + kq * 8;
        short8 af = *(const short8*)&h2L[c15 * 264 + k0];
        for (int j = 0; j < 4; j++) {
            int col = w * 64 + j * 16 + c15;
            short8 bf = *(const short8*)(L2p + col * 256 + k0);
            acc[j] = __builtin_amdgcn_mfma_f32_16x16x32_bf16(af, bf, acc[j], 0, 0, 0);
        }
    }
    for (int j = 0; j < 4; j++) {
        int col = w * 64 + j * 16 + c15;
        float bias = biasF[896 + col];
        for (int r = 0; r < 4; r++) {
            int pr = pbase + kq * 4 + r;
            int bb2 = pr >> 8, p = pr & 255;
            float v = acc[j][r] + bias; v = v > 0.f ? v : 0.f;
            float sc = sslW[bb2 * 512 + p] + 1.f;
            float sh = sslW[bb2 * 512 + 256 + p];
            outLF[((size_t)bb2 * 256 + col) * 256 + p] = v * sc + sh;
        }
    }
}

extern "C" void kernel_launch(void* const* d_in, const int* in_sizes, int n_in,
                              void* d_out, int out_size, void* d_ws, size_t ws_size,
                              hipStream_t stream) {
    const void* xyz    = d_in[0];
    const void* feat   = d_in[1];
    const void* bsize  = d_in[2];
    const void* blabel = d_in[3];
    const void* ts     = d_in[4];
    const int* inds    = (const int*)d_in[5];
    const void* mw0 = d_in[6];  const void* mb0 = d_in[7];
    const void* mw1 = d_in[8];  const void* mb1 = d_in[9];
    const void* mw2 = d_in[10]; const void* mb2 = d_in[11];
    const void* lw0 = d_in[12]; const void* lb0 = d_in[13];
    const void* lw1 = d_in[14]; const void* lb1 = d_in[15];
    const void* lw2 = d_in[16]; const void* lb2 = d_in[17];
    const void* tw0 = d_in[18]; const void* tb0 = d_in[19];
    const void* tw1 = d_in[20]; const void* tb1 = d_in[21];
    const void* bw  = d_in[22]; const void* bb  = d_in[23];
    const void* tlw0 = d_in[24]; const void* tlb0 = d_in[25];
    const void* tlw1 = d_in[26]; const void* tlb1 = d_in[27];
    const void* blw  = d_in[28]; const void* blb  = d_in[29];

    float* out = (float*)d_out;
    float* outXyz  = out;
    float* outNF   = out + 6144;
    float* outLF   = out + 268288;
    float* outInds = out + 792576;

    char* ws = (char*)d_ws;
    int*   flag  = (int*)(ws + 0);
    u16*   W0p   = (u16*)(ws + 64);
    u16*   W1p   = (u16*)(ws + 73792);
    u16*   W2p   = (u16*)(ws + 106560);
    u16*   L0p   = (u16*)(ws + 139328);
    u16*   L1p   = (u16*)(ws + 221248);
    u16*   L2p   = (u16*)(ws + 352320);
    float* biasF = (float*)(ws + 483392);
    float* ssW   = (float*)(ws + 488000);
    float* sslW  = (float*)(ws + 496192);
    float* cenW  = (float*)(ws + 512576);
    int*   sidx  = (int*)(ws + 537152);
    u16*   nfB   = (u16*)(ws + 799296);
    float* h0W   = (float*)(ws + 1323584);   //  16,384
    float* tembW = (float*)(ws + 1339968);   //  16,384
    float* g0W   = (float*)(ws + 1356352);   //  32,768
    float* temblW= (float*)(ws + 1389120);   //  32,768
    u16*   featT = (u16*)(ws + 1421888);     //  tier A: 81,920,000 / tier B: 10,240,000
    const size_t NEED_A = 1421888ull + 81920000ull;
    const size_t NEED_B = 1421888ull + 10240000ull;
    int tier = (ws_size >= NEED_A) ? 2 : ((ws_size >= NEED_B) ? 1 : 0);

    k_detect<<<dim3(1), dim3(64), 0, stream>>>((const u16*)xyz, flag);
    k_repack<<<dim3(949), dim3(256), 0, stream>>>(flag, mw0, mb0, mw1, mb1, mw2, mb2,
                                                  lw0, lb0, lw1, lb1, lw2, lb2,
                                                  W0p, W1p, W2p, L0p, L1p, L2p, biasF);

    // time-MLP chains (parallel GEMV layers)
    k_lin<1, 0><<<dim3(128), dim3(256), 0, stream>>>(flag, ts, tw0, tb0, h0W, 128, 512);
    k_lin<2, 2><<<dim3(128), dim3(256), 0, stream>>>(flag, h0W, tw1, tb1, tembW, 512, 512);
    k_lin<0, 2><<<dim3(64),  dim3(256), 0, stream>>>(flag, tembW, bw, bb, ssW, 512, 256);
    k_lin<1, 1><<<dim3(256), dim3(256), 0, stream>>>(flag, ts, tlw0, tlb0, g0W, 256, 1024);
    k_lin<2, 2><<<dim3(256), dim3(256), 0, stream>>>(flag, g0W, tlw1, tlb1, temblW, 1024, 1024);
    k_lin<0, 2><<<dim3(128), dim3(256), 0, stream>>>(flag, temblW, blw, blb, sslW, 1024, 512);

    k_sample<<<dim3(2048), dim3(256), 0, stream>>>(flag, xyz, bsize, inds, sidx, cenW, outXyz, outInds);

    if (tier == 2) {
        k_transpose<<<dim3(313, 4, BB), dim3(64, 4), 0, stream>>>(flag, feat, featT, 0);
        k_mlp1<<<dim3(1024), dim3(256), 0, stream>>>(flag, featT, feat, 0, 2, xyz, sidx, cenW, ssW,
                                                     W0p, W1p, W2p, biasF, nfB, outNF);
    } else if (tier == 1) {
        for (int b = 0; b < BB; b++) {
            k_transpose<<<dim3(313, 4, 1), dim3(64, 4), 0, stream>>>(flag, feat, featT, b);
            k_mlp1<<<dim3(128), dim3(256), 0, stream>>>(flag, featT, feat, b * 128, 1, xyz, sidx, cenW, ssW,
                                                        W0p, W1p, W2p, biasF, nfB, outNF);
        }
    } else {
        k_mlp1<<<dim3(1024), dim3(256), 0, stream>>>(flag, featT, feat, 0, 0, xyz, sidx, cenW, ssW,
                                                     W0p, W1p, W2p, biasF, nfB, outNF);
    }

    k_label<<<dim3(128), dim3(256), 0, stream>>>(flag, blabel, nfB, L0p, L1p, L2p, biasF, sslW, outLF);
}

// Round 2
// 427.522 us; speedup vs baseline: 1.3683x; 1.1029x over previous
//
#include <hip/hip_runtime.h>
#include <math.h>

#define BB 8
#define NN 20000
#define PP 256
#define SSAMP 32
#define CC 256

typedef unsigned short u16;
typedef unsigned int u32;
typedef __attribute__((ext_vector_type(8))) short short8;
typedef __attribute__((ext_vector_type(4))) float f32x4;

__device__ __forceinline__ float b2f(u16 u) {
    union { u32 i; float f; } x; x.i = ((u32)u) << 16; return x.f;
}
__device__ __forceinline__ u16 f2b(float f) {
    union { float f; u32 i; } x; x.f = f;
    u32 i = x.i;
    i += 0x7fffu + ((i >> 16) & 1u);
    return (u16)(i >> 16);
}
__device__ __forceinline__ float rnd_bf(float f) { return b2f(f2b(f)); }
__device__ __forceinline__ float geluf(float x) {
    return 0.5f * x * (1.0f + erff(x * 0.7071067811865476f));
}
__device__ __forceinline__ float siluf(float x) {
    return x / (1.0f + expf(-x));
}
__device__ __forceinline__ f32x4 fz4() { f32x4 z = {0.f,0.f,0.f,0.f}; return z; }

// dtype-adaptive loads: flag=1 -> f32 input, flag=0 -> bf16 input
__device__ __forceinline__ float ldf(const void* p, size_t i, int f32f) {
    return f32f ? ((const float*)p)[i] : b2f(((const u16*)p)[i]);
}
__device__ __forceinline__ u16 ldw(const void* p, size_t i, int f32f) {
    return f32f ? f2b(((const float*)p)[i]) : ((const u16*)p)[i];
}

// ---------------- inline dtype detection (per-wave, no global flag) ----------
// All waves probe the same 64 addresses -> identical ballot -> identical flag.
__device__ __forceinline__ int detect_f32d(const void* xyz) {
    int lane = threadIdx.x & 63;
    u16 u = ((const u16*)xyz)[(size_t)lane * 7496];
    int e = (u >> 7) & 0xFF;
    bool inR = (e >= 0x70) && (e <= 0x85);
    unsigned long long m = __ballot(inR);
    return (__popcll(m) < 48) ? 1 : 0;
}

// ---------------- repack body: weights -> bf16 blobs, biases -> f32 ----------
__device__ __forceinline__ void repack_body(int f32f, int rb, int tid,
        const void* mw0, const void* mw1, const void* mw2,
        const void* lw0, const void* lw1, const void* lw2,
        const void* mb0, const void* mb1, const void* mb2,
        const void* lb0, const void* lb1, const void* lb2,
        u16* __restrict__ W0p, u16* __restrict__ W1p, u16* __restrict__ W2p,
        u16* __restrict__ L0p, u16* __restrict__ L1p, u16* __restrict__ L2p,
        float* __restrict__ biasF) {
    int i = rb * 256 + tid;
    if (i < 36864) {
        int o = i / 288, c = i % 288;
        u16 v = 0;
        if (c < 256) v = ldw(mw0, o * 259 + 3 + c, f32f);
        else if (c < 259) v = ldw(mw0, o * 259 + (c - 256), f32f);
        W0p[i] = v;
    } else if (i < 53248) {
        W1p[i - 36864] = ldw(mw1, i - 36864, f32f);
    } else if (i < 69632) {
        W2p[i - 53248] = ldw(mw2, i - 53248, f32f);
    } else if (i < 110592) {
        int j = i - 69632;
        int o = j / 160, c = j % 160;
        L0p[j] = (c < 146) ? ldw(lw0, o * 146 + c, f32f) : (u16)0;
    } else if (i < 176128) {
        L1p[i - 110592] = ldw(lw1, i - 110592, f32f);
    } else if (i < 241664) {
        L2p[i - 176128] = ldw(lw2, i - 176128, f32f);
    } else if (i < 242816) {
        int j = i - 241664;
        float v;
        if (j < 128) v = ldf(mb0, j, f32f);
        else if (j < 256) v = ldf(mb1, j - 128, f32f);
        else if (j < 384) v = ldf(mb2, j - 256, f32f);
        else if (j < 640) v = ldf(lb0, j - 384, f32f);
        else if (j < 896) v = ldf(lb1, j - 640, f32f);
        else v = ldf(lb2, j - 896, f32f);
        biasF[j] = v;
    }
}

// ---------------- transpose body: feat [B,C,N] tile -> bf16 [.,N,C] ----------
__device__ __forceinline__ void transpose_body(int f32f, const void* __restrict__ feat,
        u16* __restrict__ featT, int n0i, int c0i, int bz, int b0, int tid,
        u16 (*tile)[66]) {
    int c0 = c0i * 64, n0 = n0i * 64;
    int b = b0 + bz;
    int tx = tid & 63, ty = tid >> 6;
    const size_t fb = (size_t)b * CC * NN;
    for (int i = 0; i < 16; i++) {
        int cl = ty * 16 + i;
        int n = n0 + tx;
        if (n < NN) tile[cl][tx] = ldw(feat, fb + (size_t)(c0 + cl) * NN + n, f32f);
    }
    __syncthreads();
    const size_t tb = (size_t)bz * NN * CC;
    for (int i = 0; i < 16; i++) {
        int nl = ty * 16 + i;
        int n = n0 + nl;
        if (n < NN) featT[tb + (size_t)n * CC + c0 + tx] = tile[tx][nl];
    }
}

// ---------------- time-MLP layer body: wave-per-row GEMV, 8 batches/wave -----
// ACT: 0=none 1=gelu 2=silu ; SRC: 0=sinusoid128(ts) 1=sinusoid256(ts) 2=f32 [8][K]
template<int ACT, int SRC>
__device__ __forceinline__ void lin_body(int f32f, const void* __restrict__ xin,
        const void* __restrict__ W, const void* __restrict__ bias,
        float* __restrict__ out, int K, int O, int rb, int tid, float* xs) {
    if (SRC == 2) {
        const float* X = (const float*)xin;
        for (int i = tid; i < 8 * K; i += 256) xs[i] = X[i];
    } else {
        const int half = (SRC == 0) ? 64 : 128;
        const int dim = half * 2;
        const float cst = (SRC == 0) ? (logf(10000.f) / 63.f) : (logf(10000.f) / 127.f);
        for (int i = tid; i < 8 * dim; i += 256) {
            int b = i / dim, j = i % dim;
            float t = ldf(xin, b, f32f);
            int jj = (j < half) ? j : (j - half);
            float e = t * expf(-(float)jj * cst);
            xs[i] = (j < half) ? sinf(e) : cosf(e);
        }
    }
    __syncthreads();
    int lane = tid & 63, wv = tid >> 6;
    int r = rb * 4 + wv;
    if (r >= O) return;
    float acc[8] = {0.f, 0.f, 0.f, 0.f, 0.f, 0.f, 0.f, 0.f};
    for (int k = lane; k < K; k += 64) {
        float wval = ldf(W, (size_t)r * K + k, f32f);
        #pragma unroll
        for (int b = 0; b < 8; b++) acc[b] += wval * xs[b * K + k];
    }
    #pragma unroll
    for (int b = 0; b < 8; b++) {
        acc[b] += __shfl_xor(acc[b], 1);
        acc[b] += __shfl_xor(acc[b], 2);
        acc[b] += __shfl_xor(acc[b], 4);
        acc[b] += __shfl_xor(acc[b], 8);
        acc[b] += __shfl_xor(acc[b], 16);
        acc[b] += __shfl_xor(acc[b], 32);
    }
    if (lane == 0) {
        float bv = ldf(bias, r, f32f);
        #pragma unroll
        for (int b = 0; b < 8; b++) {
            float v = acc[b] + bv;
            if (ACT == 1) v = geluf(v);
            else if (ACT == 2) v = siluf(v);
            out[b * O + r] = v;
        }
    }
}

// ---------------- sampler body: one block (4 waves) per proposal -------------
// 1024 pts/iter, all loads hoisted; parity-buffered wcnt -> ONE sync per iter.
// sBuf writes are disjoint across iterations (positions strictly increase).
__device__ __forceinline__ void sample_body(int f32f, const void* __restrict__ xyz,
        const void* __restrict__ bsize, const int* __restrict__ inds,
        int* __restrict__ sidx, float* __restrict__ cenW,
        float* __restrict__ outXyz, float* __restrict__ outInds,
        int pg, int tid, int* sBuf, int* wcnt) {
    int lane = tid & 63, w = tid >> 6;
    int b = pg >> 8;
    int ind = inds[pg];
    ind = ind < 0 ? 0 : (ind >= NN ? NN - 1 : ind);
    if (tid < SSAMP) sBuf[tid] = 0;   // ordered before first sBuf writes by iter-0 sync
    size_t xb = (size_t)b * NN * 3;
    float cx = ldf(xyz, xb + (size_t)ind * 3 + 0, f32f);
    float cy = ldf(xyz, xb + (size_t)ind * 3 + 1, f32f);
    float cz = ldf(xyz, xb + (size_t)ind * 3 + 2, f32f);
    float hx = 0.5f * ldf(bsize, pg * 3 + 0, f32f);
    float hy = 0.5f * ldf(bsize, pg * 3 + 1, f32f);
    float hz = 0.5f * ldf(bsize, pg * 3 + 2, f32f);
    int cnt = 0, par = 0;
    const unsigned long long lmask = (1ull << lane) - 1ull;
    for (int base = 0; base < NN; base += 1024, par ^= 4) {
        int nb = base + w * 256 + lane;
        int nn[4];
        float px[4], py[4], pz[4];
        #pragma unroll
        for (int u = 0; u < 4; u++) {
            int n = nb + u * 64;
            nn[u] = n;
            int nc = n < NN ? n : NN - 1;
            size_t a = xb + (size_t)nc * 3;
            px[u] = ldf(xyz, a, f32f);
            py[u] = ldf(xyz, a + 1, f32f);
            pz[u] = ldf(xyz, a + 2, f32f);
        }
        bool isin[4];
        unsigned long long m[4];
        int pc[4];
        int tw = 0;
        #pragma unroll
        for (int u = 0; u < 4; u++) {
            bool in_ = (nn[u] < NN) &&
                       (fabsf(px[u] - cx) <= hx) &&
                       (fabsf(py[u] - cy) <= hy) &&
                       (fabsf(pz[u] - cz) <= hz);
            isin[u] = in_;
            m[u] = __ballot(in_);
            pc[u] = (int)__popcll(m[u]);
            tw += pc[u];
        }
        if (lane == 0) wcnt[par + w] = tw;
        __syncthreads();
        int w0 = wcnt[par + 0], w1 = wcnt[par + 1], w2 = wcnt[par + 2], w3 = wcnt[par + 3];
        int total = w0 + w1 + w2 + w3;
        int prior = cnt;
        if (w >= 1) prior += w0;
        if (w >= 2) prior += w1;
        if (w >= 3) prior += w2;
        #pragma unroll
        for (int u = 0; u < 4; u++) {
            int pos = prior + (int)__popcll(m[u] & lmask);
            if (isin[u] && pos < SSAMP) sBuf[pos] = nn[u];
            prior += pc[u];
        }
        cnt += total;             // uniform across block -> uniform break
        if (cnt >= SSAMP) break;
    }
    __syncthreads();              // order sBuf writes before final reads
    int ccap = cnt < SSAMP ? cnt : SSAMP;
    if (ccap < 1) ccap = 1;
    if (tid < SSAMP) sidx[pg * SSAMP + tid] = sBuf[tid % ccap];
    if (tid < 3) {
        float cv = tid == 0 ? cx : (tid == 1 ? cy : cz);
        outXyz[pg * 3 + tid] = cv;
        cenW[pg * 3 + tid] = cv;
    }
    if (tid == 0) outInds[pg] = rnd_bf((float)ind);
}

// ---------------- K1 mega-front: sample | transpose | repack | lin layer-1 ----
__global__ __launch_bounds__(256) void k_front(
        const void* __restrict__ xyz, const void* __restrict__ feat,
        const void* __restrict__ bsize, const int* __restrict__ inds,
        const void* __restrict__ ts,
        const void* mw0, const void* mw1, const void* mw2,
        const void* lw0, const void* lw1, const void* lw2,
        const void* mb0, const void* mb1, const void* mb2,
        const void* lb0, const void* lb1, const void* lb2,
        const void* tw0, const void* tb0,
        const void* tlw0, const void* tlb0,
        u16* __restrict__ featT, int nTrans,
        int* __restrict__ sidx, float* __restrict__ cenW,
        float* __restrict__ outXyz, float* __restrict__ outInds,
        u16* __restrict__ W0p, u16* __restrict__ W1p, u16* __restrict__ W2p,
        u16* __restrict__ L0p, u16* __restrict__ L1p, u16* __restrict__ L2p,
        float* __restrict__ biasF, float* __restrict__ h0W, float* __restrict__ g0W) {
    __shared__ __align__(16) char smem[8448];
    int tid = threadIdx.x;
    int f32f = detect_f32d(xyz);
    unsigned bx = blockIdx.x;
    unsigned s1 = 2048u + (unsigned)nTrans;
    unsigned s2 = s1 + 949u;
    unsigned s3 = s2 + 128u;
    if (bx < 2048u) {
        sample_body(f32f, xyz, bsize, inds, sidx, cenW, outXyz, outInds,
                    (int)bx, tid, (int*)smem, (int*)(smem + 128));
    } else if (bx < s1) {
        int t = (int)(bx - 2048u);
        transpose_body(f32f, feat, featT, t % 313, (t / 313) & 3, t / 1252, 0, tid,
                       (u16(*)[66])smem);
    } else if (bx < s2) {
        repack_body(f32f, (int)(bx - s1), tid, mw0, mw1, mw2, lw0, lw1, lw2,
                    mb0, mb1, mb2, lb0, lb1, lb2, W0p, W1p, W2p, L0p, L1p, L2p, biasF);
    } else if (bx < s3) {
        lin_body<1, 0>(f32f, ts, tw0, tb0, h0W, 128, 512, (int)(bx - s2), tid, (float*)smem);
    } else {
        lin_body<1, 1>(f32f, ts, tlw0, tlb0, g0W, 256, 1024, (int)(bx - s3), tid, (float*)smem);
    }
}

// ---------------- K2: layer-2 of both time-MLP chains ------------------------
__global__ __launch_bounds__(256) void k_mid2(const void* __restrict__ xyz,
        const void* tw1, const void* tb1, const void* tlw1, const void* tlb1,
        const float* __restrict__ h0W, const float* __restrict__ g0W,
        float* __restrict__ tembW, float* __restrict__ temblW) {
    __shared__ float xs[8 * 1024];
    int tid = threadIdx.x;
    int f32f = detect_f32d(xyz);
    unsigned bx = blockIdx.x;
    if (bx < 128u) lin_body<2, 2>(f32f, h0W, tw1, tb1, tembW, 512, 512, (int)bx, tid, xs);
    else lin_body<2, 2>(f32f, g0W, tlw1, tlb1, temblW, 1024, 1024, (int)(bx - 128u), tid, xs);
}

// ---------------- K3: layer-3 of both time-MLP chains ------------------------
__global__ __launch_bounds__(256) void k_mid3(const void* __restrict__ xyz,
        const void* bw, const void* bb, const void* blw, const void* blb,
        const float* __restrict__ tembW, const float* __restrict__ temblW,
        float* __restrict__ ssW, float* __restrict__ sslW) {
    __shared__ float xs[8 * 1024];
    int tid = threadIdx.x;
    int f32f = detect_f32d(xyz);
    unsigned bx = blockIdx.x;
    if (bx < 64u) lin_body<0, 2>(f32f, tembW, bw, bb, ssW, 512, 256, (int)bx, tid, xs);
    else lin_body<0, 2>(f32f, temblW, blw, blb, sslW, 1024, 512, (int)(bx - 64u), tid, xs);
}

// ---------------- standalone transpose (tier-1 path) -------------------------
__global__ __launch_bounds__(256) void k_transpose(const void* __restrict__ xyz,
                                                   const void* __restrict__ feat,
                                                   u16* __restrict__ featT, int b0) {
    __shared__ u16 tile[64][66];
    int f32f = detect_f32d(xyz);
    transpose_body(f32f, feat, featT, blockIdx.x, blockIdx.y, blockIdx.z, b0,
                   threadIdx.x, tile);
}

// ---------------- gather + 3-layer MFMA MLP + maxpool + fused FiLM ----------
// tier: 2 = full featT [8*NN,C]; 1 = single-batch featB [NN,C]; 0 = scalar gather
__global__ __launch_bounds__(256) void k_mlp1(
        const u16* __restrict__ featT, const void* __restrict__ feat,
        int blockOff, int tier,
        const void* __restrict__ xyz, const int* __restrict__ sidx,
        const float* __restrict__ cenW, const float* __restrict__ ssW,
        const u16* __restrict__ W0p, const u16* __restrict__ W1p,
        const u16* __restrict__ W2p, const float* __restrict__ biasF,
        u16* __restrict__ nfB, float* __restrict__ outNF) {
    __shared__ u16 gA[64 * 296];
    __shared__ u16 h1s[64 * 136];
    __shared__ int nrowS[64];
    __shared__ float centS[8];
    int f32f = detect_f32d(xyz);
    int tid = threadIdx.x;
    int pbase = (blockIdx.x + blockOff) * 2;
    int b = pbase >> 8;
    if (tid < 64) {
        int n = sidx[pbase * SSAMP + tid];
        nrowS[tid] = n < 0 ? 0 : (n >= NN ? NN - 1 : n);
    }
    if (tid < 6) centS[tid] = cenW[pbase * 3 + tid];
    for (int e = tid; e < 64 * 32; e += 256) {
        int row = e >> 5, c2 = e & 31;
        if (c2 >= 8 && c2 < 28)
            *(u32*)&gA[row * 296 + 256 + (c2 - 8) * 2] = 0u;
    }
    __syncthreads();
    if (tier >= 1) {
        size_t rowBase = (tier == 2) ? ((size_t)b * NN) : 0;
        for (int e = tid; e < 64 * 32; e += 256) {
            int row = e >> 5, seg = e & 31;
            int n = nrowS[row];
            uint4 v = *(const uint4*)(featT + (rowBase + n) * CC + seg * 8);
            *(uint4*)&gA[row * 296 + seg * 8] = v;
        }
    } else {
        int row = tid & 63;
        int n = nrowS[row];
        const size_t fb = (size_t)b * CC * NN;
        int cbase = tid >> 6;
        for (int it = 0; it < 64; it++) {
            int cch = it * 4 + cbase;
            gA[row * 296 + cch] = ldw(feat, fb + (size_t)cch * NN + n, f32f);
        }
    }
    if (tid < 64) {
        int row = tid, q = row >> 5;
        int n = nrowS[row];
        size_t a = ((size_t)b * NN + n) * 3;
        for (int d = 0; d < 3; d++) {
            float gv = ldf(xyz, a + d, f32f) - centS[q * 3 + d];
            gA[row * 296 + 256 + d] = f2b(gv);
        }
    }
    __syncthreads();

    int lane = tid & 63, w = tid >> 6;
    int c15 = lane & 15, kq = lane >> 4;
    f32x4 acc[4][2];

    // ---- layer 1: K=288 ----
    for (int mt = 0; mt < 4; mt++) for (int j = 0; j < 2; j++) acc[mt][j] = fz4();
    for (int ks = 0; ks < 9; ks++) {
        int k0 = ks * 32 + kq * 8;
        short8 af[4];
        for (int mt = 0; mt < 4; mt++)
            af[mt] = *(const short8*)&gA[(mt * 16 + c15) * 296 + k0];
        for (int j = 0; j < 2; j++) {
            int col = w * 32 + j * 16 + c15;
            short8 bf = *(const short8*)(W0p + col * 288 + k0);
            for (int mt = 0; mt < 4; mt++)
                acc[mt][j] = __builtin_amdgcn_mfma_f32_16x16x32_bf16(af[mt], bf, acc[mt][j], 0, 0, 0);
        }
    }
    for (int j = 0; j < 2; j++) {
        int col = w * 32 + j * 16 + c15;
        float bias = biasF[col];
        for (int mt = 0; mt < 4; mt++)
            for (int r = 0; r < 4; r++) {
                float v = acc[mt][j][r] + bias;
                v = v > 0.f ? v : 0.f;
                h1s[(mt * 16 + kq * 4 + r) * 136 + col] = f2b(v);
            }
    }
    __syncthreads();

    // ---- layer 2: K=128, h2 aliases gA ----
    u16* h2s = gA;
    for (int mt = 0; mt < 4; mt++) for (int j = 0; j < 2; j++) acc[mt][j] = fz4();
    for (int ks = 0; ks < 4; ks++) {
        int k0 = ks * 32 + kq * 8;
        short8 af[4];
        for (int mt = 0; mt < 4; mt++)
            af[mt] = *(const short8*)&h1s[(mt * 16 + c15) * 136 + k0];
        for (int j = 0; j < 2; j++) {
            int col = w * 32 + j * 16 + c15;
            short8 bf = *(const short8*)(W1p + col * 128 + k0);
            for (int mt = 0; mt < 4; mt++)
                acc[mt][j] = __builtin_amdgcn_mfma_f32_16x16x32_bf16(af[mt], bf, acc[mt][j], 0, 0, 0);
        }
    }
    __syncthreads();
    for (int j = 0; j < 2; j++) {
        int col = w * 32 + j * 16 + c15;
        float bias = biasF[128 + col];
        for (int mt = 0; mt < 4; mt++)
            for (int r = 0; r < 4; r++) {
                float v = acc[mt][j][r] + bias;
                v = v > 0.f ? v : 0.f;
                h2s[(mt * 16 + kq * 4 + r) * 136 + col] = f2b(v);
            }
    }
    __syncthreads();

    // ---- layer 3: K=128 + maxpool + fused FiLM ----
    for (int mt = 0; mt < 4; mt++) for (int j = 0; j < 2; j++) acc[mt][j] = fz4();
    for (int ks = 0; ks < 4; ks++) {
        int k0 = ks * 32 + kq * 8;
        short8 af[4];
        for (int mt = 0; mt < 4; mt++)
            af[mt] = *(const short8*)&h2s[(mt * 16 + c15) * 136 + k0];
        for (int j = 0; j < 2; j++) {
            int col = w * 32 + j * 16 + c15;
            short8 bf = *(const short8*)(W2p + col * 128 + k0);
            for (int mt = 0; mt < 4; mt++)
                acc[mt][j] = __builtin_amdgcn_mfma_f32_16x16x32_bf16(af[mt], bf, acc[mt][j], 0, 0, 0);
        }
    }
    int pA = pbase & 255, pB = (pbase + 1) & 255;
    float scA = ssW[b * 256 + (pA & 127)] + 1.f, shA = ssW[b * 256 + 128 + (pA & 127)];
    float scB = ssW[b * 256 + (pB & 127)] + 1.f, shB = ssW[b * 256 + 128 + (pB & 127)];
    for (int j = 0; j < 2; j++) {
        int col = w * 32 + j * 16 + c15;
        float bias = biasF[256 + col];
        float mA = 0.f, mB = 0.f;
        for (int mt = 0; mt < 2; mt++)
            for (int r = 0; r < 4; r++) {
                float v = acc[mt][j][r] + bias; v = v > 0.f ? v : 0.f;
                mA = fmaxf(mA, v);
            }
        for (int mt = 2; mt < 4; mt++)
            for (int r = 0; r < 4; r++) {
                float v = acc[mt][j][r] + bias; v = v > 0.f ? v : 0.f;
                mB = fmaxf(mB, v);
            }
        mA = fmaxf(mA, __shfl_xor(mA, 16)); mA = fmaxf(mA, __shfl_xor(mA, 32));
        mB = fmaxf(mB, __shfl_xor(mB, 16)); mB = fmaxf(mB, __shfl_xor(mB, 32));
        if (lane < 16) {
            nfB[(size_t)(pbase + 0) * 128 + col] = f2b(mA);
            nfB[(size_t)(pbase + 1) * 128 + col] = f2b(mB);
            outNF[((size_t)b * 128 + col) * 256 + pA] = mA * scA + shA;
            outNF[((size_t)b * 128 + col) * 256 + pB] = mB * scB + shB;
        }
    }
}

// ---------------- label MFMA MLP + fused FiLM: 16 proposals/block ----------------
__global__ __launch_bounds__(256) void k_label(const void* __restrict__ xyz,
        const void* __restrict__ blabel,
        const u16* __restrict__ nfB, const u16* __restrict__ L0p,
        const u16* __restrict__ L1p, const u16* __restrict__ L2p,
        const float* __restrict__ biasF, const float* __restrict__ sslW,
        float* __restrict__ outLF) {
    __shared__ u16 liS[16 * 168];
    __shared__ u16 h1L[16 * 264];
    __shared__ u16 h2L[16 * 264];
    int f32f = detect_f32d(xyz);
    int tid = threadIdx.x;
    int pbase = blockIdx.x * 16;
    for (int e = tid; e < 16 * 160; e += 256) {
        int row = e / 160, c = e % 160;
        int pg = pbase + row;
        u16 v = 0;
        if (c < 18) v = ldw(blabel, pg * 18 + c, f32f);
        else if (c < 146) v = nfB[(size_t)pg * 128 + (c - 18)];
        liS[row * 168 + c] = v;
    }
    __syncthreads();
    int lane = tid & 63, w = tid >> 6;
    int c15 = lane & 15, kq = lane >> 4;
    f32x4 acc[4];

    // layer 1: K=160
    for (int j = 0; j < 4; j++) acc[j] = fz4();
    for (int ks = 0; ks < 5; ks++) {
        int k0 = ks * 32 + kq * 8;
        short8 af = *(const short8*)&liS[c15 * 168 + k0];
        for (int j = 0; j < 4; j++) {
            int col = w * 64 + j * 16 + c15;
            short8 bf = *(const short8*)(L0p + col * 160 + k0);
            acc[j] = __builtin_amdgcn_mfma_f32_16x16x32_bf16(af, bf, acc[j], 0, 0, 0);
        }
    }
    for (int j = 0; j < 4; j++) {
        int col = w * 64 + j * 16 + c15;
        float bias = biasF[384 + col];
        for (int r = 0; r < 4; r++) {
            float v = acc[j][r] + bias; v = v > 0.f ? v : 0.f;
            h1L[(kq * 4 + r) * 264 + col] = f2b(v);
        }
    }
    __syncthreads();

    // layer 2: K=256
    for (int j = 0; j < 4; j++) acc[j] = fz4();
    for (int ks = 0; ks < 8; ks++) {
        int k0 = ks * 32 + kq * 8;
        short8 af = *(const short8*)&h1L[c15 * 264 + k0];
        for (int j = 0; j < 4; j++) {
            int col = w * 64 + j * 16 + c15;
            short8 bf = *(const short8*)(L1p + col * 256 + k0);
            acc[j] = __builtin_amdgcn_mfma_f32_16x16x32_bf16(af, bf, acc[j], 0, 0, 0);
        }
    }
    for (int j = 0; j < 4; j++) {
        int col = w * 64 + j * 16 + c15;
        float bias = biasF[640 + col];
        for (int r = 0; r < 4; r++) {
            float v = acc[j][r] + bias; v = v > 0.f ? v : 0.f;
            h2L[(kq * 4 + r) * 264 + col] = f2b(v);
        }
    }
    __syncthreads();

    // layer 3: K=256 + fused FiLM -> outLF (f32)
    for (int j = 0; j < 4; j++) acc[j] = fz4();
    for (int ks = 0; ks < 8; ks++) {
        int k0 = ks * 32 + kq * 8;
        short8 af = *(const short8*)&h2L[c15 * 264 + k0];
        for (int j = 0; j < 4; j++) {
            int col = w * 64 + j * 16 + c15;
            short8 bf = *(const short8*)(L2p + col * 256 + k0);
            acc[j] = __builtin_amdgcn_mfma_f32_16x16x32_bf16(af, bf, acc[j], 0, 0, 0);
        }
    }
    for (int j = 0; j < 4; j++) {
        int col = w * 64 + j * 16 + c15;
        float bias = biasF[896 + col];
        for (int r = 0; r < 4; r++) {
            int pr = pbase + kq * 4 + r;
            int bb2 = pr >> 8, p = pr & 255;
            float v = acc[j][r] + bias; v = v > 0.f ? v : 0.f;
            float sc = sslW[bb2 * 512 + p] + 1.f;
            float sh = sslW[bb2 * 512 + 256 + p];
            outLF[((size_t)bb2 * 256 + col) * 256 + p] = v * sc + sh;
        }
    }
}

extern "C" void kernel_launch(void* const* d_in, const int* in_sizes, int n_in,
                              void* d_out, int out_size, void* d_ws, size_t ws_size,
                              hipStream_t stream) {
    const void* xyz    = d_in[0];
    const void* feat   = d_in[1];
    const void* bsize  = d_in[2];
    const void* blabel = d_in[3];
    const void* ts     = d_in[4];
    const int* inds    = (const int*)d_in[5];
    const void* mw0 = d_in[6];  const void* mb0 = d_in[7];
    const void* mw1 = d_in[8];  const void* mb1 = d_in[9];
    const void* mw2 = d_in[10]; const void* mb2 = d_in[11];
    const void* lw0 = d_in[12]; const void* lb0 = d_in[13];
    const void* lw1 = d_in[14]; const void* lb1 = d_in[15];
    const void* lw2 = d_in[16]; const void* lb2 = d_in[17];
    const void* tw0 = d_in[18]; const void* tb0 = d_in[19];
    const void* tw1 = d_in[20]; const void* tb1 = d_in[21];
    const void* bw  = d_in[22]; const void* bb  = d_in[23];
    const void* tlw0 = d_in[24]; const void* tlb0 = d_in[25];
    const void* tlw1 = d_in[26]; const void* tlb1 = d_in[27];
    const void* blw  = d_in[28]; const void* blb  = d_in[29];

    float* out = (float*)d_out;
    float* outXyz  = out;
    float* outNF   = out + 6144;
    float* outLF   = out + 268288;
    float* outInds = out + 792576;

    char* ws = (char*)d_ws;
    u16*   W0p   = (u16*)(ws + 64);
    u16*   W1p   = (u16*)(ws + 73792);
    u16*   W2p   = (u16*)(ws + 106560);
    u16*   L0p   = (u16*)(ws + 139328);
    u16*   L1p   = (u16*)(ws + 221248);
    u16*   L2p   = (u16*)(ws + 352320);
    float* biasF = (float*)(ws + 483392);
    float* ssW   = (float*)(ws + 488000);
    float* sslW  = (float*)(ws + 496192);
    float* cenW  = (float*)(ws + 512576);
    int*   sidx  = (int*)(ws + 537152);
    u16*   nfB   = (u16*)(ws + 799296);
    float* h0W   = (float*)(ws + 1323584);   //  16,384
    float* tembW = (float*)(ws + 1339968);   //  16,384
    float* g0W   = (float*)(ws + 1356352);   //  32,768
    float* temblW= (float*)(ws + 1389120);   //  32,768
    u16*   featT = (u16*)(ws + 1421888);     //  tier A: 81,920,000 / tier B: 10,240,000
    const size_t NEED_A = 1421888ull + 81920000ull;
    const size_t NEED_B = 1421888ull + 10240000ull;
    int tier = (ws_size >= NEED_A) ? 2 : ((ws_size >= NEED_B) ? 1 : 0);

    int nTrans = (tier == 2) ? 10016 : 0;
    unsigned gFront = 2048u + (unsigned)nTrans + 949u + 128u + 256u;
    k_front<<<dim3(gFront), dim3(256), 0, stream>>>(
        xyz, feat, bsize, inds, ts,
        mw0, mw1, mw2, lw0, lw1, lw2,
        mb0, mb1, mb2, lb0, lb1, lb2,
        tw0, tb0, tlw0, tlb0,
        featT, nTrans, sidx, cenW, outXyz, outInds,
        W0p, W1p, W2p, L0p, L1p, L2p, biasF, h0W, g0W);

    k_mid2<<<dim3(384), dim3(256), 0, stream>>>(xyz, tw1, tb1, tlw1, tlb1,
                                                h0W, g0W, tembW, temblW);
    k_mid3<<<dim3(192), dim3(256), 0, stream>>>(xyz, bw, bb, blw, blb,
                                                tembW, temblW, ssW, sslW);

    if (tier == 2) {
        k_mlp1<<<dim3(1024), dim3(256), 0, stream>>>(featT, feat, 0, 2, xyz, sidx, cenW, ssW,
                                                     W0p, W1p, W2p, biasF, nfB, outNF);
    } else if (tier == 1) {
        for (int b = 0; b < BB; b++) {
            k_transpose<<<dim3(313, 4, 1), dim3(256), 0, stream>>>(xyz, feat, featT, b);
            k_mlp1<<<dim3(128), dim3(256), 0, stream>>>(featT, feat, b * 128, 1, xyz, sidx, cenW, ssW,
                                                        W0p, W1p, W2p, biasF, nfB, outNF);
        }
    } else {
        k_mlp1<<<dim3(1024), dim3(256), 0, stream>>>(featT, feat, 0, 0, xyz, sidx, cenW, ssW,
                                                     W0p, W1p, W2p, biasF, nfB, outNF);
    }

    k_label<<<dim3(128), dim3(256), 0, stream>>>(xyz, blabel, nfB, L0p, L1p, L2p, biasF, sslW, outLF);
}

// Round 3
// 423.821 us; speedup vs baseline: 1.3802x; 1.0087x over previous
//
#include <hip/hip_runtime.h>
#include <math.h>

#define BB 8
#define NN 20000
#define PP 256
#define SSAMP 32
#define CC 256

typedef unsigned short u16;
typedef unsigned int u32;
typedef __attribute__((ext_vector_type(8))) short short8;
typedef __attribute__((ext_vector_type(4))) float f32x4;

__device__ __forceinline__ float b2f(u16 u) {
    union { u32 i; float f; } x; x.i = ((u32)u) << 16; return x.f;
}
__device__ __forceinline__ u16 f2b(float f) {
    union { float f; u32 i; } x; x.f = f;
    u32 i = x.i;
    i += 0x7fffu + ((i >> 16) & 1u);
    return (u16)(i >> 16);
}
__device__ __forceinline__ float rnd_bf(float f) { return b2f(f2b(f)); }
__device__ __forceinline__ float geluf(float x) {
    return 0.5f * x * (1.0f + erff(x * 0.7071067811865476f));
}
__device__ __forceinline__ float siluf(float x) {
    return x / (1.0f + expf(-x));
}
__device__ __forceinline__ f32x4 fz4() { f32x4 z = {0.f,0.f,0.f,0.f}; return z; }

// dtype-adaptive loads: flag=1 -> f32 input, flag=0 -> bf16 input
__device__ __forceinline__ float ldf(const void* p, size_t i, int f32f) {
    return f32f ? ((const float*)p)[i] : b2f(((const u16*)p)[i]);
}
__device__ __forceinline__ u16 ldw(const void* p, size_t i, int f32f) {
    return f32f ? f2b(((const float*)p)[i]) : ((const u16*)p)[i];
}

// ---------------- inline dtype detection (per-wave, no global flag) ----------
__device__ __forceinline__ int detect_f32d(const void* xyz) {
    int lane = threadIdx.x & 63;
    u16 u = ((const u16*)xyz)[(size_t)lane * 7496];
    int e = (u >> 7) & 0xFF;
    bool inR = (e >= 0x70) && (e <= 0x85);
    unsigned long long m = __ballot(inR);
    return (__popcll(m) < 48) ? 1 : 0;
}

// ---------------- repack body: weights -> bf16 blobs, biases -> f32 ----------
__device__ __forceinline__ void repack_body(int f32f, int rb, int tid,
        const void* mw0, const void* mw1, const void* mw2,
        const void* lw0, const void* lw1, const void* lw2,
        const void* mb0, const void* mb1, const void* mb2,
        const void* lb0, const void* lb1, const void* lb2,
        u16* __restrict__ W0p, u16* __restrict__ W1p, u16* __restrict__ W2p,
        u16* __restrict__ L0p, u16* __restrict__ L1p, u16* __restrict__ L2p,
        float* __restrict__ biasF) {
    int i = rb * 256 + tid;
    if (i < 36864) {
        int o = i / 288, c = i % 288;
        u16 v = 0;
        if (c < 256) v = ldw(mw0, o * 259 + 3 + c, f32f);
        else if (c < 259) v = ldw(mw0, o * 259 + (c - 256), f32f);
        W0p[i] = v;
    } else if (i < 53248) {
        W1p[i - 36864] = ldw(mw1, i - 36864, f32f);
    } else if (i < 69632) {
        W2p[i - 53248] = ldw(mw2, i - 53248, f32f);
    } else if (i < 110592) {
        int j = i - 69632;
        int o = j / 160, c = j % 160;
        L0p[j] = (c < 146) ? ldw(lw0, o * 146 + c, f32f) : (u16)0;
    } else if (i < 176128) {
        L1p[i - 110592] = ldw(lw1, i - 110592, f32f);
    } else if (i < 241664) {
        L2p[i - 176128] = ldw(lw2, i - 176128, f32f);
    } else if (i < 242816) {
        int j = i - 241664;
        float v;
        if (j < 128) v = ldf(mb0, j, f32f);
        else if (j < 256) v = ldf(mb1, j - 128, f32f);
        else if (j < 384) v = ldf(mb2, j - 256, f32f);
        else if (j < 640) v = ldf(lb0, j - 384, f32f);
        else if (j < 896) v = ldf(lb1, j - 640, f32f);
        else v = ldf(lb2, j - 896, f32f);
        biasF[j] = v;
    }
}

// ---------------- transpose body: feat [B,C,N] tile -> bf16 [.,N,C] ----------
// Vectorized: float4 (f32) / ushort4 (bf16) global loads along n, ushort4
// stores along c. LDS tile [c][n] stride 66 (benign banks). Boundary tile
// (n0=19968) falls back to the scalar guarded path.
__device__ __forceinline__ void transpose_body(int f32f, const void* __restrict__ feat,
        u16* __restrict__ featT, int n0i, int c0i, int bz, int b0, int tid,
        u16 (*tile)[66]) {
    int c0 = c0i * 64, n0 = n0i * 64;
    int b = b0 + bz;
    const size_t fb = (size_t)b * CC * NN;
    const size_t tb = (size_t)bz * NN * CC;
    if (n0 + 64 <= NN) {
        int n4 = tid & 15, ci = tid >> 4;        // ci 0..15
        if (f32f) {
            #pragma unroll
            for (int pass = 0; pass < 4; pass++) {
                int c = pass * 16 + ci;
                const float* src = (const float*)feat + fb + (size_t)(c0 + c) * NN + n0 + n4 * 4;
                float4 v = *(const float4*)src;
                tile[c][n4 * 4 + 0] = f2b(v.x);
                tile[c][n4 * 4 + 1] = f2b(v.y);
                tile[c][n4 * 4 + 2] = f2b(v.z);
                tile[c][n4 * 4 + 3] = f2b(v.w);
            }
        } else {
            #pragma unroll
            for (int pass = 0; pass < 4; pass++) {
                int c = pass * 16 + ci;
                const u16* src = (const u16*)feat + fb + (size_t)(c0 + c) * NN + n0 + n4 * 4;
                ushort4 v = *(const ushort4*)src;
                tile[c][n4 * 4 + 0] = v.x;
                tile[c][n4 * 4 + 1] = v.y;
                tile[c][n4 * 4 + 2] = v.z;
                tile[c][n4 * 4 + 3] = v.w;
            }
        }
        __syncthreads();
        int c4 = tid & 15, ni = tid >> 4;        // ni 0..15
        #pragma unroll
        for (int pass = 0; pass < 4; pass++) {
            int n = pass * 16 + ni;
            ushort4 o;
            o.x = tile[c4 * 4 + 0][n];
            o.y = tile[c4 * 4 + 1][n];
            o.z = tile[c4 * 4 + 2][n];
            o.w = tile[c4 * 4 + 3][n];
            *(ushort4*)(featT + tb + (size_t)(n0 + n) * CC + c0 + c4 * 4) = o;
        }
    } else {
        int tx = tid & 63, ty = tid >> 6;
        for (int i = 0; i < 16; i++) {
            int cl = ty * 16 + i;
            int n = n0 + tx;
            if (n < NN) tile[cl][tx] = ldw(feat, fb + (size_t)(c0 + cl) * NN + n, f32f);
        }
        __syncthreads();
        for (int i = 0; i < 16; i++) {
            int nl = ty * 16 + i;
            int n = n0 + nl;
            if (n < NN) featT[tb + (size_t)n * CC + c0 + tx] = tile[tx][nl];
        }
    }
}

// ---------------- time-MLP layer body: wave-per-row GEMV, 8 batches/wave -----
// ACT: 0=none 1=gelu 2=silu ; SRC: 0=sinusoid128(ts) 1=sinusoid256(ts) 2=f32 [8][K]
template<int ACT, int SRC>
__device__ __forceinline__ void lin_body(int f32f, const void* __restrict__ xin,
        const void* __restrict__ W, const void* __restrict__ bias,
        float* __restrict__ out, int K, int O, int rb, int tid, float* xs) {
    if (SRC == 2) {
        const float* X = (const float*)xin;
        for (int i = tid; i < 8 * K; i += 256) xs[i] = X[i];
    } else {
        const int half = (SRC == 0) ? 64 : 128;
        const int dim = half * 2;
        const float cst = (SRC == 0) ? (logf(10000.f) / 63.f) : (logf(10000.f) / 127.f);
        for (int i = tid; i < 8 * dim; i += 256) {
            int b = i / dim, j = i % dim;
            float t = ldf(xin, b, f32f);
            int jj = (j < half) ? j : (j - half);
            float e = t * expf(-(float)jj * cst);
            xs[i] = (j < half) ? sinf(e) : cosf(e);
        }
    }
    __syncthreads();
    int lane = tid & 63, wv = tid >> 6;
    int r = rb * 4 + wv;
    if (r >= O) return;
    float acc[8] = {0.f, 0.f, 0.f, 0.f, 0.f, 0.f, 0.f, 0.f};
    for (int k = lane; k < K; k += 64) {
        float wval = ldf(W, (size_t)r * K + k, f32f);
        #pragma unroll
        for (int b = 0; b < 8; b++) acc[b] += wval * xs[b * K + k];
    }
    #pragma unroll
    for (int b = 0; b < 8; b++) {
        acc[b] += __shfl_xor(acc[b], 1);
        acc[b] += __shfl_xor(acc[b], 2);
        acc[b] += __shfl_xor(acc[b], 4);
        acc[b] += __shfl_xor(acc[b], 8);
        acc[b] += __shfl_xor(acc[b], 16);
        acc[b] += __shfl_xor(acc[b], 32);
    }
    if (lane == 0) {
        float bv = ldf(bias, r, f32f);
        #pragma unroll
        for (int b = 0; b < 8; b++) {
            float v = acc[b] + bv;
            if (ACT == 1) v = geluf(v);
            else if (ACT == 2) v = siluf(v);
            out[b * O + r] = v;
        }
    }
}

// ---------------- sampler body: one block (4 waves) per proposal -------------
// 1024 pts/iter; chunk i+1's loads are issued BEFORE chunk i's ballot/sync so
// memory latency overlaps the reduction. Parity-buffered wcnt -> one sync/iter.
__device__ __forceinline__ void sample_body(int f32f, const void* __restrict__ xyz,
        const void* __restrict__ bsize, const int* __restrict__ inds,
        int* __restrict__ sidx, float* __restrict__ cenW,
        float* __restrict__ outXyz, float* __restrict__ outInds,
        int pg, int tid, int* sBuf, int* wcnt) {
    int lane = tid & 63, w = tid >> 6;
    int b = pg >> 8;
    int ind = inds[pg];
    ind = ind < 0 ? 0 : (ind >= NN ? NN - 1 : ind);
    if (tid < SSAMP) sBuf[tid] = 0;
    size_t xb = (size_t)b * NN * 3;
    float cx = ldf(xyz, xb + (size_t)ind * 3 + 0, f32f);
    float cy = ldf(xyz, xb + (size_t)ind * 3 + 1, f32f);
    float cz = ldf(xyz, xb + (size_t)ind * 3 + 2, f32f);
    float hx = 0.5f * ldf(bsize, pg * 3 + 0, f32f);
    float hy = 0.5f * ldf(bsize, pg * 3 + 1, f32f);
    float hz = 0.5f * ldf(bsize, pg * 3 + 2, f32f);
    int cnt = 0, par = 0;
    const unsigned long long lmask = (1ull << lane) - 1ull;
    int nn[4];
    float px[4], py[4], pz[4];
    #pragma unroll
    for (int u = 0; u < 4; u++) {
        int n = w * 256 + lane + u * 64;
        nn[u] = n;
        int nc = n < NN ? n : NN - 1;
        size_t a = xb + (size_t)nc * 3;
        px[u] = ldf(xyz, a, f32f);
        py[u] = ldf(xyz, a + 1, f32f);
        pz[u] = ldf(xyz, a + 2, f32f);
    }
    for (int base = 0;;) {
        int nbase = base + 1024;
        bool more = nbase < NN;
        int qn[4];
        float qx[4], qy[4], qz[4];
        if (more) {                      // prefetch next chunk (overlaps sync)
            #pragma unroll
            for (int u = 0; u < 4; u++) {
                int n = nbase + w * 256 + lane + u * 64;
                qn[u] = n;
                int nc = n < NN ? n : NN - 1;
                size_t a = xb + (size_t)nc * 3;
                qx[u] = ldf(xyz, a, f32f);
                qy[u] = ldf(xyz, a + 1, f32f);
                qz[u] = ldf(xyz, a + 2, f32f);
            }
        }
        bool isin[4];
        unsigned long long m[4];
        int pc[4];
        int tw = 0;
        #pragma unroll
        for (int u = 0; u < 4; u++) {
            bool in_ = (nn[u] < NN) &&
                       (fabsf(px[u] - cx) <= hx) &&
                       (fabsf(py[u] - cy) <= hy) &&
                       (fabsf(pz[u] - cz) <= hz);
            isin[u] = in_;
            m[u] = __ballot(in_);
            pc[u] = (int)__popcll(m[u]);
            tw += pc[u];
        }
        if (lane == 0) wcnt[par + w] = tw;
        __syncthreads();
        int w0 = wcnt[par + 0], w1 = wcnt[par + 1], w2 = wcnt[par + 2], w3 = wcnt[par + 3];
        int total = w0 + w1 + w2 + w3;
        int prior = cnt;
        if (w >= 1) prior += w0;
        if (w >= 2) prior += w1;
        if (w >= 3) prior += w2;
        #pragma unroll
        for (int u = 0; u < 4; u++) {
            int pos = prior + (int)__popcll(m[u] & lmask);
            if (isin[u] && pos < SSAMP) sBuf[pos] = nn[u];
            prior += pc[u];
        }
        cnt += total;                    // uniform across block
        if (cnt >= SSAMP || !more) break;
        par ^= 4;
        base = nbase;
        #pragma unroll
        for (int u = 0; u < 4; u++) {
            nn[u] = qn[u]; px[u] = qx[u]; py[u] = qy[u]; pz[u] = qz[u];
        }
    }
    __syncthreads();                     // order sBuf writes before final reads
    int ccap = cnt < SSAMP ? cnt : SSAMP;
    if (ccap < 1) ccap = 1;
    if (tid < SSAMP) sidx[pg * SSAMP + tid] = sBuf[tid % ccap];
    if (tid < 3) {
        float cv = tid == 0 ? cx : (tid == 1 ? cy : cz);
        outXyz[pg * 3 + tid] = cv;
        cenW[pg * 3 + tid] = cv;
    }
    if (tid == 0) outInds[pg] = rnd_bf((float)ind);
}

// ---------------- gather + 3-layer MFMA MLP + maxpool (raw max -> nfF) -------
// LDS: single 37,888B buffer; h1s/h2s alias it (extra barrier) -> 4 blocks/CU.
__device__ __forceinline__ void mlp1_body(int f32f,
        const u16* __restrict__ featT, const void* __restrict__ feat,
        int pbase, int tier,
        const void* __restrict__ xyz, const int* __restrict__ sidx,
        const float* __restrict__ cenW,
        const u16* __restrict__ W0p, const u16* __restrict__ W1p,
        const u16* __restrict__ W2p, const float* __restrict__ biasF,
        u16* __restrict__ nfB, float* __restrict__ nfF,
        int tid, u16* gA, int* nrowS, float* centS) {
    int b = pbase >> 8;
    if (tid < 64) {
        int n = sidx[pbase * SSAMP + tid];
        nrowS[tid] = n < 0 ? 0 : (n >= NN ? NN - 1 : n);
    }
    if (tid < 6) centS[tid] = cenW[pbase * 3 + tid];
    for (int e = tid; e < 64 * 32; e += 256) {
        int row = e >> 5, c2 = e & 31;
        if (c2 >= 8 && c2 < 28)
            *(u32*)&gA[row * 296 + 256 + (c2 - 8) * 2] = 0u;
    }
    __syncthreads();
    if (tier >= 1) {
        size_t rowBase = (tier == 2) ? ((size_t)b * NN) : 0;
        for (int e = tid; e < 64 * 32; e += 256) {
            int row = e >> 5, seg = e & 31;
            int n = nrowS[row];
            uint4 v = *(const uint4*)(featT + (rowBase + n) * CC + seg * 8);
            *(uint4*)&gA[row * 296 + seg * 8] = v;
        }
    } else {
        int row = tid & 63;
        int n = nrowS[row];
        const size_t fb = (size_t)b * CC * NN;
        int cbase = tid >> 6;
        for (int it = 0; it < 64; it++) {
            int cch = it * 4 + cbase;
            gA[row * 296 + cch] = ldw(feat, fb + (size_t)cch * NN + n, f32f);
        }
    }
    if (tid < 64) {
        int row = tid, q = row >> 5;
        int n = nrowS[row];
        size_t a = ((size_t)b * NN + n) * 3;
        for (int d = 0; d < 3; d++) {
            float gv = ldf(xyz, a + d, f32f) - centS[q * 3 + d];
            gA[row * 296 + 256 + d] = f2b(gv);
        }
    }
    __syncthreads();

    int lane = tid & 63, w = tid >> 6;
    int c15 = lane & 15, kq = lane >> 4;
    f32x4 acc[4][2];

    // ---- layer 1: K=288 ----
    for (int mt = 0; mt < 4; mt++) for (int j = 0; j < 2; j++) acc[mt][j] = fz4();
    for (int ks = 0; ks < 9; ks++) {
        int k0 = ks * 32 + kq * 8;
        short8 af[4];
        for (int mt = 0; mt < 4; mt++)
            af[mt] = *(const short8*)&gA[(mt * 16 + c15) * 296 + k0];
        for (int j = 0; j < 2; j++) {
            int col = w * 32 + j * 16 + c15;
            short8 bf = *(const short8*)(W0p + col * 288 + k0);
            for (int mt = 0; mt < 4; mt++)
                acc[mt][j] = __builtin_amdgcn_mfma_f32_16x16x32_bf16(af[mt], bf, acc[mt][j], 0, 0, 0);
        }
    }
    __syncthreads();                 // gA reads complete before h1s aliases it
    u16* h1s = gA;                   // [0, 8704) u16
    u16* h2s = gA + 8704;            // [8704, 17408) u16
    for (int j = 0; j < 2; j++) {
        int col = w * 32 + j * 16 + c15;
        float bias = biasF[col];
        for (int mt = 0; mt < 4; mt++)
            for (int r = 0; r < 4; r++) {
                float v = acc[mt][j][r] + bias;
                v = v > 0.f ? v : 0.f;
                h1s[(mt * 16 + kq * 4 + r) * 136 + col] = f2b(v);
            }
    }
    __syncthreads();

    // ---- layer 2: K=128 ----
    for (int mt = 0; mt < 4; mt++) for (int j = 0; j < 2; j++) acc[mt][j] = fz4();
    for (int ks = 0; ks < 4; ks++) {
        int k0 = ks * 32 + kq * 8;
        short8 af[4];
        for (int mt = 0; mt < 4; mt++)
            af[mt] = *(const short8*)&h1s[(mt * 16 + c15) * 136 + k0];
        for (int j = 0; j < 2; j++) {
            int col = w * 32 + j * 16 + c15;
            short8 bf = *(const short8*)(W1p + col * 128 + k0);
            for (int mt = 0; mt < 4; mt++)
                acc[mt][j] = __builtin_amdgcn_mfma_f32_16x16x32_bf16(af[mt], bf, acc[mt][j], 0, 0, 0);
        }
    }
    __syncthreads();
    for (int j = 0; j < 2; j++) {
        int col = w * 32 + j * 16 + c15;
        float bias = biasF[128 + col];
        for (int mt = 0; mt < 4; mt++)
            for (int r = 0; r < 4; r++) {
                float v = acc[mt][j][r] + bias;
                v = v > 0.f ? v : 0.f;
                h2s[(mt * 16 + kq * 4 + r) * 136 + col] = f2b(v);
            }
    }
    __syncthreads();

    // ---- layer 3: K=128 + maxpool -> nfB (bf16) + nfF (f32, outNF layout) ----
    for (int mt = 0; mt < 4; mt++) for (int j = 0; j < 2; j++) acc[mt][j] = fz4();
    for (int ks = 0; ks < 4; ks++) {
        int k0 = ks * 32 + kq * 8;
        short8 af[4];
        for (int mt = 0; mt < 4; mt++)
            af[mt] = *(const short8*)&h2s[(mt * 16 + c15) * 136 + k0];
        for (int j = 0; j < 2; j++) {
            int col = w * 32 + j * 16 + c15;
            short8 bf = *(const short8*)(W2p + col * 128 + k0);
            for (int mt = 0; mt < 4; mt++)
                acc[mt][j] = __builtin_amdgcn_mfma_f32_16x16x32_bf16(af[mt], bf, acc[mt][j], 0, 0, 0);
        }
    }
    int pA = pbase & 255, pB = (pbase + 1) & 255;
    for (int j = 0; j < 2; j++) {
        int col = w * 32 + j * 16 + c15;
        float bias = biasF[256 + col];
        float mA = 0.f, mB = 0.f;
        for (int mt = 0; mt < 2; mt++)
            for (int r = 0; r < 4; r++) {
                float v = acc[mt][j][r] + bias; v = v > 0.f ? v : 0.f;
                mA = fmaxf(mA, v);
            }
        for (int mt = 2; mt < 4; mt++)
            for (int r = 0; r < 4; r++) {
                float v = acc[mt][j][r] + bias; v = v > 0.f ? v : 0.f;
                mB = fmaxf(mB, v);
            }
        mA = fmaxf(mA, __shfl_xor(mA, 16)); mA = fmaxf(mA, __shfl_xor(mA, 32));
        mB = fmaxf(mB, __shfl_xor(mB, 16)); mB = fmaxf(mB, __shfl_xor(mB, 32));
        if (lane < 16) {
            nfB[(size_t)(pbase + 0) * 128 + col] = f2b(mA);
            nfB[(size_t)(pbase + 1) * 128 + col] = f2b(mB);
            nfF[((size_t)b * 128 + col) * 256 + pA] = mA;
            nfF[((size_t)b * 128 + col) * 256 + pB] = mB;
        }
    }
}

// ---------------- K1 mega-front: transpose | sample | repack | lin layer-1 ---
__global__ __launch_bounds__(256) void k_front(
        const void* __restrict__ xyz, const void* __restrict__ feat,
        const void* __restrict__ bsize, const int* __restrict__ inds,
        const void* __restrict__ ts,
        const void* mw0, const void* mw1, const void* mw2,
        const void* lw0, const void* lw1, const void* lw2,
        const void* mb0, const void* mb1, const void* mb2,
        const void* lb0, const void* lb1, const void* lb2,
        const void* tw0, const void* tb0,
        const void* tlw0, const void* tlb0,
        u16* __restrict__ featT, int nTrans,
        int* __restrict__ sidx, float* __restrict__ cenW,
        float* __restrict__ outXyz, float* __restrict__ outInds,
        u16* __restrict__ W0p, u16* __restrict__ W1p, u16* __restrict__ W2p,
        u16* __restrict__ L0p, u16* __restrict__ L1p, u16* __restrict__ L2p,
        float* __restrict__ biasF, float* __restrict__ h0W, float* __restrict__ g0W) {
    __shared__ __align__(16) char smem[8448];
    int tid = threadIdx.x;
    int f32f = detect_f32d(xyz);
    unsigned bx = blockIdx.x;
    unsigned s1 = (unsigned)nTrans + 2048u;
    unsigned s2 = s1 + 949u;
    unsigned s3 = s2 + 128u;
    if (bx < (unsigned)nTrans) {
        int t = (int)bx;
        transpose_body(f32f, feat, featT, t % 313, (t / 313) & 3, t / 1252, 0, tid,
                       (u16(*)[66])smem);
    } else if (bx < s1) {
        sample_body(f32f, xyz, bsize, inds, sidx, cenW, outXyz, outInds,
                    (int)(bx - (unsigned)nTrans), tid, (int*)smem, (int*)(smem + 128));
    } else if (bx < s2) {
        repack_body(f32f, (int)(bx - s1), tid, mw0, mw1, mw2, lw0, lw1, lw2,
                    mb0, mb1, mb2, lb0, lb1, lb2, W0p, W1p, W2p, L0p, L1p, L2p, biasF);
    } else if (bx < s3) {
        lin_body<1, 0>(f32f, ts, tw0, tb0, h0W, 128, 512, (int)(bx - s2), tid, (float*)smem);
    } else {
        lin_body<1, 1>(f32f, ts, tlw0, tlb0, g0W, 256, 1024, (int)(bx - s3), tid, (float*)smem);
    }
}

// ---------------- K2: mlp1 + layer-2 of both time-MLP chains -----------------
__global__ __launch_bounds__(256) void k_mid(int nMlp, int blockOff, int tier,
        const u16* __restrict__ featT, const void* __restrict__ feat,
        const void* __restrict__ xyz, const int* __restrict__ sidx,
        const float* __restrict__ cenW,
        const u16* __restrict__ W0p, const u16* __restrict__ W1p,
        const u16* __restrict__ W2p, const float* __restrict__ biasF,
        u16* __restrict__ nfB, float* __restrict__ nfF,
        const void* tw1, const void* tb1, const void* tlw1, const void* tlb1,
        const float* __restrict__ h0W, const float* __restrict__ g0W,
        float* __restrict__ tembW, float* __restrict__ temblW) {
    __shared__ __align__(16) char smem[38176];
    int tid = threadIdx.x;
    int f32f = detect_f32d(xyz);
    int bx = (int)blockIdx.x;
    if (bx < nMlp) {
        mlp1_body(f32f, featT, feat, (bx + blockOff) * 2, tier, xyz, sidx, cenW,
                  W0p, W1p, W2p, biasF, nfB, nfF, tid,
                  (u16*)smem, (int*)(smem + 37888), (float*)(smem + 38144));
    } else {
        int lb = bx - nMlp;
        float* xs = (float*)smem;
        if (lb < 128) lin_body<2, 2>(f32f, h0W, tw1, tb1, tembW, 512, 512, lb, tid, xs);
        else lin_body<2, 2>(f32f, g0W, tlw1, tlb1, temblW, 1024, 1024, lb - 128, tid, xs);
    }
}

// ---------------- K3: layer-3 of both time-MLP chains ------------------------
__global__ __launch_bounds__(256) void k_lin3(const void* __restrict__ xyz,
        const void* bw, const void* bb, const void* blw, const void* blb,
        const float* __restrict__ tembW, const float* __restrict__ temblW,
        float* __restrict__ ssW, float* __restrict__ sslW) {
    __shared__ float xs[8 * 1024];
    int tid = threadIdx.x;
    int f32f = detect_f32d(xyz);
    unsigned bx = blockIdx.x;
    if (bx < 64u) lin_body<0, 2>(f32f, tembW, bw, bb, ssW, 512, 256, (int)bx, tid, xs);
    else lin_body<0, 2>(f32f, temblW, blw, blb, sslW, 1024, 512, (int)(bx - 64u), tid, xs);
}

// ---------------- standalone transpose (tier-1 path) -------------------------
__global__ __launch_bounds__(256) void k_transpose(const void* __restrict__ xyz,
                                                   const void* __restrict__ feat,
                                                   u16* __restrict__ featT, int b0) {
    __shared__ u16 tile[64][66];
    int f32f = detect_f32d(xyz);
    transpose_body(f32f, feat, featT, blockIdx.x, blockIdx.y, blockIdx.z, b0,
                   threadIdx.x, tile);
}

// ---------------- K4: label MFMA MLP + FiLM | NF FiLM ------------------------
__global__ __launch_bounds__(256) void k_tail(const void* __restrict__ xyz,
        const void* __restrict__ blabel,
        const u16* __restrict__ nfB, const u16* __restrict__ L0p,
        const u16* __restrict__ L1p, const u16* __restrict__ L2p,
        const float* __restrict__ biasF, const float* __restrict__ sslW,
        const float* __restrict__ ssW, const float* __restrict__ nfF,
        float* __restrict__ outLF, float* __restrict__ outNF) {
    __shared__ u16 liS[16 * 168];
    __shared__ u16 h1L[16 * 264];
    __shared__ u16 h2L[16 * 264];
    int f32f = detect_f32d(xyz);
    int tid = threadIdx.x;
    unsigned bxu = blockIdx.x;
    if (bxu >= 128u) {
        // NF FiLM: outNF = nfF * (scale+1) + shift  (coalesced, p fastest)
        int base = (int)(bxu - 128u) * 4096;
        #pragma unroll
        for (int i = 0; i < 16; i++) {
            int idx = base + i * 256 + tid;
            int p = idx & 255;
            int cb = idx >> 8;
            int b = cb >> 7;
            float sc = ssW[b * 256 + (p & 127)] + 1.f;
            float sh = ssW[b * 256 + 128 + (p & 127)];
            outNF[idx] = nfF[idx] * sc + sh;
        }
        return;
    }
    int pbase = (int)bxu * 16;
    for (int e = tid; e < 16 * 160; e += 256) {
        int row = e / 160, c = e % 160;
        int pg = pbase + row;
        u16 v = 0;
        if (c < 18) v = ldw(blabel, pg * 18 + c, f32f);
        else if (c < 146) v = nfB[(size_t)pg * 128 + (c - 18)];
        liS[row * 168 + c] = v;
    }
    __syncthreads();
    int lane = tid & 63, w = tid >> 6;
    int c15 = lane & 15, kq = lane >> 4;
    f32x4 acc[4];

    // layer 1: K=160
    for (int j = 0; j < 4; j++) acc[j] = fz4();
    for (int ks = 0; ks < 5; ks++) {
        int k0 = ks * 32 + kq * 8;
        short8 af = *(const short8*)&liS[c15 * 168 + k0];
        for (int j = 0; j < 4; j++) {
            int col = w * 64 + j * 16 + c15;
            short8 bf = *(const short8*)(L0p + col * 160 + k0);
            acc[j] = __builtin_amdgcn_mfma_f32_16x16x32_bf16(af, bf, acc[j], 0, 0, 0);
        }
    }
    for (int j = 0; j < 4; j++) {
        int col = w * 64 + j * 16 + c15;
        float bias = biasF[384 + col];
        for (int r = 0; r < 4; r++) {
            float v = acc[j][r] + bias; v = v > 0.f ? v : 0.f;
            h1L[(kq * 4 + r) * 264 + col] = f2b(v);
        }
    }
    __syncthreads();

    // layer 2: K=256
    for (int j = 0; j < 4; j++) acc[j] = fz4();
    for (int ks = 0; ks < 8; ks++) {
        int k0 = ks * 32 + kq * 8;
        short8 af = *(const short8*)&h1L[c15 * 264 + k0];
        for (int j = 0; j < 4; j++) {
            int col = w * 64 + j * 16 + c15;
            short8 bf = *(const short8*)(L1p + col * 256 + k0);
            acc[j] = __builtin_amdgcn_mfma_f32_16x16x32_bf16(af, bf, acc[j], 0, 0, 0);
        }
    }
    for (int j = 0; j < 4; j++) {
        int col = w * 64 + j * 16 + c15;
        float bias = biasF[640 + col];
        for (int r = 0; r < 4; r++) {
            float v = acc[j][r] + bias; v = v > 0.f ? v : 0.f;
            h2L[(kq * 4 + r) * 264 + col] = f2b(v);
        }
    }
    __syncthreads();

    // layer 3: K=256 + fused FiLM -> outLF (f32)
    for (int j = 0; j < 4; j++) acc[j] = fz4();
    for (int ks = 0; ks < 8; ks++) {
        int k0 = ks * 32 + kq * 8;
        short8 af = *(const short8*)&h2L[c15 * 264 + k0];
        for (int j = 0; j < 4; j++) {
            int col = w * 64 + j * 16 + c15;
            short8 bf = *(const short8*)(L2p + col * 256 + k0);
            acc[j] = __builtin_amdgcn_mfma_f32_16x16x32_bf16(af, bf, acc[j], 0, 0, 0);
        }
    }
    for (int j = 0; j < 4; j++) {
        int col = w * 64 + j * 16 + c15;
        float bias = biasF[896 + col];
        for (int r = 0; r < 4; r++) {
            int pr = pbase + kq * 4 + r;
            int bb2 = pr >> 8, p = pr & 255;
            float v = acc[j][r] + bias; v = v > 0.f ? v : 0.f;
            float sc = sslW[bb2 * 512 + p] + 1.f;
            float sh = sslW[bb2 * 512 + 256 + p];
            outLF[((size_t)bb2 * 256 + col) * 256 + p] = v * sc + sh;
        }
    }
}

extern "C" void kernel_launch(void* const* d_in, const int* in_sizes, int n_in,
                              void* d_out, int out_size, void* d_ws, size_t ws_size,
                              hipStream_t stream) {
    const void* xyz    = d_in[0];
    const void* feat   = d_in[1];
    const void* bsize  = d_in[2];
    const void* blabel = d_in[3];
    const void* ts     = d_in[4];
    const int* inds    = (const int*)d_in[5];
    const void* mw0 = d_in[6];  const void* mb0 = d_in[7];
    const void* mw1 = d_in[8];  const void* mb1 = d_in[9];
    const void* mw2 = d_in[10]; const void* mb2 = d_in[11];
    const void* lw0 = d_in[12]; const void* lb0 = d_in[13];
    const void* lw1 = d_in[14]; const void* lb1 = d_in[15];
    const void* lw2 = d_in[16]; const void* lb2 = d_in[17];
    const void* tw0 = d_in[18]; const void* tb0 = d_in[19];
    const void* tw1 = d_in[20]; const void* tb1 = d_in[21];
    const void* bw  = d_in[22]; const void* bb  = d_in[23];
    const void* tlw0 = d_in[24]; const void* tlb0 = d_in[25];
    const void* tlw1 = d_in[26]; const void* tlb1 = d_in[27];
    const void* blw  = d_in[28]; const void* blb  = d_in[29];

    float* out = (float*)d_out;
    float* outXyz  = out;
    float* outNF   = out + 6144;
    float* outLF   = out + 268288;
    float* outInds = out + 792576;

    char* ws = (char*)d_ws;
    u16*   W0p   = (u16*)(ws + 64);
    u16*   W1p   = (u16*)(ws + 73792);
    u16*   W2p   = (u16*)(ws + 106560);
    u16*   L0p   = (u16*)(ws + 139328);
    u16*   L1p   = (u16*)(ws + 221248);
    u16*   L2p   = (u16*)(ws + 352320);
    float* biasF = (float*)(ws + 483392);
    float* ssW   = (float*)(ws + 488000);
    float* sslW  = (float*)(ws + 496192);
    float* cenW  = (float*)(ws + 512576);
    int*   sidx  = (int*)(ws + 537152);
    u16*   nfB   = (u16*)(ws + 799296);      // 524,288
    float* h0W   = (float*)(ws + 1323584);   //  16,384
    float* tembW = (float*)(ws + 1339968);   //  16,384
    float* g0W   = (float*)(ws + 1356352);   //  32,768
    float* temblW= (float*)(ws + 1389120);   //  32,768
    float* nfF   = (float*)(ws + 1421888);   //  1,048,576
    u16*   featT = (u16*)(ws + 2470464);     //  tier A: 81,920,000 / tier B: 10,240,000
    const size_t NEED_A = 2470464ull + 81920000ull;
    const size_t NEED_B = 2470464ull + 10240000ull;
    int tier = (ws_size >= NEED_A) ? 2 : ((ws_size >= NEED_B) ? 1 : 0);

    int nTrans = (tier == 2) ? 10016 : 0;
    unsigned gFront = (unsigned)nTrans + 2048u + 949u + 128u + 256u;
    k_front<<<dim3(gFront), dim3(256), 0, stream>>>(
        xyz, feat, bsize, inds, ts,
        mw0, mw1, mw2, lw0, lw1, lw2,
        mb0, mb1, mb2, lb0, lb1, lb2,
        tw0, tb0, tlw0, tlb0,
        featT, nTrans, sidx, cenW, outXyz, outInds,
        W0p, W1p, W2p, L0p, L1p, L2p, biasF, h0W, g0W);

    if (tier == 2) {
        k_mid<<<dim3(1024 + 384), dim3(256), 0, stream>>>(1024, 0, 2,
            featT, feat, xyz, sidx, cenW, W0p, W1p, W2p, biasF, nfB, nfF,
            tw1, tb1, tlw1, tlb1, h0W, g0W, tembW, temblW);
    } else if (tier == 1) {
        for (int b = 0; b < BB; b++) {
            k_transpose<<<dim3(313, 4, 1), dim3(256), 0, stream>>>(xyz, feat, featT, b);
            k_mid<<<dim3(128), dim3(256), 0, stream>>>(128, b * 128, 1,
                featT, feat, xyz, sidx, cenW, W0p, W1p, W2p, biasF, nfB, nfF,
                tw1, tb1, tlw1, tlb1, h0W, g0W, tembW, temblW);
        }
        k_mid<<<dim3(384), dim3(256), 0, stream>>>(0, 0, 1,
            featT, feat, xyz, sidx, cenW, W0p, W1p, W2p, biasF, nfB, nfF,
            tw1, tb1, tlw1, tlb1, h0W, g0W, tembW, temblW);
    } else {
        k_mid<<<dim3(1024 + 384), dim3(256), 0, stream>>>(1024, 0, 0,
            featT, feat, xyz, sidx, cenW, W0p, W1p, W2p, biasF, nfB, nfF,
            tw1, tb1, tlw1, tlb1, h0W, g0W, tembW, temblW);
    }

    k_lin3<<<dim3(192), dim3(256), 0, stream>>>(xyz, bw, bb, blw, blb,
                                                tembW, temblW, ssW, sslW);

    k_tail<<<dim3(128 + 64), dim3(256), 0, stream>>>(xyz, blabel, nfB,
        L0p, L1p, L2p, biasF, sslW, ssW, nfF, outLF, outNF);
}

// Round 4
// 417.651 us; speedup vs baseline: 1.4006x; 1.0148x over previous
//
#include <hip/hip_runtime.h>
#include <math.h>

#define BB 8
#define NN 20000
#define PP 256
#define SSAMP 32
#define CC 256

typedef unsigned short u16;
typedef unsigned int u32;
typedef __attribute__((ext_vector_type(8))) short short8;
typedef __attribute__((ext_vector_type(4))) float f32x4;

struct __align__(4) f3v { float x, y, z; };

__device__ __forceinline__ float b2f(u16 u) {
    union { u32 i; float f; } x; x.i = ((u32)u) << 16; return x.f;
}
__device__ __forceinline__ u16 f2b(float f) {
    union { float f; u32 i; } x; x.f = f;
    u32 i = x.i;
    i += 0x7fffu + ((i >> 16) & 1u);
    return (u16)(i >> 16);
}
__device__ __forceinline__ float rnd_bf(float f) { return b2f(f2b(f)); }
__device__ __forceinline__ float geluf(float x) {
    return 0.5f * x * (1.0f + erff(x * 0.7071067811865476f));
}
__device__ __forceinline__ float siluf(float x) {
    return x / (1.0f + expf(-x));
}
__device__ __forceinline__ f32x4 fz4() { f32x4 z = {0.f,0.f,0.f,0.f}; return z; }

// dtype-adaptive loads: flag=1 -> f32 input, flag=0 -> bf16 input
__device__ __forceinline__ float ldf(const void* p, size_t i, int f32f) {
    return f32f ? ((const float*)p)[i] : b2f(((const u16*)p)[i]);
}
__device__ __forceinline__ u16 ldw(const void* p, size_t i, int f32f) {
    return f32f ? f2b(((const float*)p)[i]) : ((const u16*)p)[i];
}

// ---------------- inline dtype detection (per-wave, no global flag) ----------
__device__ __forceinline__ int detect_f32d(const void* xyz) {
    int lane = threadIdx.x & 63;
    u16 u = ((const u16*)xyz)[(size_t)lane * 7496];
    int e = (u >> 7) & 0xFF;
    bool inR = (e >= 0x70) && (e <= 0x85);
    unsigned long long m = __ballot(inR);
    return (__popcll(m) < 48) ? 1 : 0;
}

// ---------------- repack body: weights -> bf16 blobs, biases -> f32 ----------
__device__ __forceinline__ void repack_body(int f32f, int rb, int tid,
        const void* mw0, const void* mw1, const void* mw2,
        const void* lw0, const void* lw1, const void* lw2,
        const void* mb0, const void* mb1, const void* mb2,
        const void* lb0, const void* lb1, const void* lb2,
        u16* __restrict__ W0p, u16* __restrict__ W1p, u16* __restrict__ W2p,
        u16* __restrict__ L0p, u16* __restrict__ L1p, u16* __restrict__ L2p,
        float* __restrict__ biasF) {
    int i = rb * 256 + tid;
    if (i < 36864) {
        int o = i / 288, c = i % 288;
        u16 v = 0;
        if (c < 256) v = ldw(mw0, o * 259 + 3 + c, f32f);
        else if (c < 259) v = ldw(mw0, o * 259 + (c - 256), f32f);
        W0p[i] = v;
    } else if (i < 53248) {
        W1p[i - 36864] = ldw(mw1, i - 36864, f32f);
    } else if (i < 69632) {
        W2p[i - 53248] = ldw(mw2, i - 53248, f32f);
    } else if (i < 110592) {
        int j = i - 69632;
        int o = j / 160, c = j % 160;
        L0p[j] = (c < 146) ? ldw(lw0, o * 146 + c, f32f) : (u16)0;
    } else if (i < 176128) {
        L1p[i - 110592] = ldw(lw1, i - 110592, f32f);
    } else if (i < 241664) {
        L2p[i - 176128] = ldw(lw2, i - 176128, f32f);
    } else if (i < 242816) {
        int j = i - 241664;
        float v;
        if (j < 128) v = ldf(mb0, j, f32f);
        else if (j < 256) v = ldf(mb1, j - 128, f32f);
        else if (j < 384) v = ldf(mb2, j - 256, f32f);
        else if (j < 640) v = ldf(lb0, j - 384, f32f);
        else if (j < 896) v = ldf(lb1, j - 640, f32f);
        else v = ldf(lb2, j - 896, f32f);
        biasF[j] = v;
    }
}

// ---------------- transpose body: feat [B,C,N] tile -> bf16 [.,N,C] ----------
// Vectorized: float4 (f32) / ushort4 (bf16) global loads along n, ushort4
// stores along c. LDS tile [c][n] stride 66. Boundary tile scalar fallback.
__device__ __forceinline__ void transpose_body(int f32f, const void* __restrict__ feat,
        u16* __restrict__ featT, int n0i, int c0i, int bz, int b0, int tid,
        u16 (*tile)[66]) {
    int c0 = c0i * 64, n0 = n0i * 64;
    int b = b0 + bz;
    const size_t fb = (size_t)b * CC * NN;
    const size_t tb = (size_t)bz * NN * CC;
    if (n0 + 64 <= NN) {
        int n4 = tid & 15, ci = tid >> 4;        // ci 0..15
        if (f32f) {
            #pragma unroll
            for (int pass = 0; pass < 4; pass++) {
                int c = pass * 16 + ci;
                const float* src = (const float*)feat + fb + (size_t)(c0 + c) * NN + n0 + n4 * 4;
                float4 v = *(const float4*)src;
                tile[c][n4 * 4 + 0] = f2b(v.x);
                tile[c][n4 * 4 + 1] = f2b(v.y);
                tile[c][n4 * 4 + 2] = f2b(v.z);
                tile[c][n4 * 4 + 3] = f2b(v.w);
            }
        } else {
            #pragma unroll
            for (int pass = 0; pass < 4; pass++) {
                int c = pass * 16 + ci;
                const u16* src = (const u16*)feat + fb + (size_t)(c0 + c) * NN + n0 + n4 * 4;
                ushort4 v = *(const ushort4*)src;
                tile[c][n4 * 4 + 0] = v.x;
                tile[c][n4 * 4 + 1] = v.y;
                tile[c][n4 * 4 + 2] = v.z;
                tile[c][n4 * 4 + 3] = v.w;
            }
        }
        __syncthreads();
        int c4 = tid & 15, ni = tid >> 4;        // ni 0..15
        #pragma unroll
        for (int pass = 0; pass < 4; pass++) {
            int n = pass * 16 + ni;
            ushort4 o;
            o.x = tile[c4 * 4 + 0][n];
            o.y = tile[c4 * 4 + 1][n];
            o.z = tile[c4 * 4 + 2][n];
            o.w = tile[c4 * 4 + 3][n];
            *(ushort4*)(featT + tb + (size_t)(n0 + n) * CC + c0 + c4 * 4) = o;
        }
    } else {
        int tx = tid & 63, ty = tid >> 6;
        for (int i = 0; i < 16; i++) {
            int cl = ty * 16 + i;
            int n = n0 + tx;
            if (n < NN) tile[cl][tx] = ldw(feat, fb + (size_t)(c0 + cl) * NN + n, f32f);
        }
        __syncthreads();
        for (int i = 0; i < 16; i++) {
            int nl = ty * 16 + i;
            int n = n0 + nl;
            if (n < NN) featT[tb + (size_t)n * CC + c0 + tx] = tile[tx][nl];
        }
    }
}

// ---------------- time-MLP layer body: wave-per-row GEMV, 8 batches/wave -----
// ACT: 0=none 1=gelu 2=silu ; SRC: 0=sinusoid128(ts) 1=sinusoid256(ts) 2=f32 [8][K]
template<int ACT, int SRC>
__device__ __forceinline__ void lin_body(int f32f, const void* __restrict__ xin,
        const void* __restrict__ W, const void* __restrict__ bias,
        float* __restrict__ out, int K, int O, int rb, int tid, float* xs) {
    if (SRC == 2) {
        const float* X = (const float*)xin;
        for (int i = tid; i < 8 * K; i += 256) xs[i] = X[i];
    } else {
        const int half = (SRC == 0) ? 64 : 128;
        const int dim = half * 2;
        const float cst = (SRC == 0) ? (logf(10000.f) / 63.f) : (logf(10000.f) / 127.f);
        for (int i = tid; i < 8 * dim; i += 256) {
            int b = i / dim, j = i % dim;
            float t = ldf(xin, b, f32f);
            int jj = (j < half) ? j : (j - half);
            float e = t * expf(-(float)jj * cst);
            xs[i] = (j < half) ? sinf(e) : cosf(e);
        }
    }
    __syncthreads();
    int lane = tid & 63, wv = tid >> 6;
    int r = rb * 4 + wv;
    if (r >= O) return;
    float acc[8] = {0.f, 0.f, 0.f, 0.f, 0.f, 0.f, 0.f, 0.f};
    for (int k = lane; k < K; k += 64) {
        float wval = ldf(W, (size_t)r * K + k, f32f);
        #pragma unroll
        for (int b = 0; b < 8; b++) acc[b] += wval * xs[b * K + k];
    }
    #pragma unroll
    for (int b = 0; b < 8; b++) {
        acc[b] += __shfl_xor(acc[b], 1);
        acc[b] += __shfl_xor(acc[b], 2);
        acc[b] += __shfl_xor(acc[b], 4);
        acc[b] += __shfl_xor(acc[b], 8);
        acc[b] += __shfl_xor(acc[b], 16);
        acc[b] += __shfl_xor(acc[b], 32);
    }
    if (lane == 0) {
        float bv = ldf(bias, r, f32f);
        #pragma unroll
        for (int b = 0; b < 8; b++) {
            float v = acc[b] + bv;
            if (ACT == 1) v = geluf(v);
            else if (ACT == 2) v = siluf(v);
            out[b * O + r] = v;
        }
    }
}

// ---------------- sampler body: one block (4 waves) per proposal -------------
// 1024 pts/iter. f32 path loads each point as ONE dwordx3 (12B) instead of
// three stride-12 dwords -> 3x fewer address-divergent vmem instructions.
// Parity-buffered wcnt -> one sync per iteration.
__device__ __forceinline__ void sample_body(int f32f, const void* __restrict__ xyz,
        const void* __restrict__ bsize, const int* __restrict__ inds,
        int* __restrict__ sidx, float* __restrict__ cenW,
        float* __restrict__ outXyz, float* __restrict__ outInds,
        int pg, int tid, int* sBuf, int* wcnt) {
    int lane = tid & 63, w = tid >> 6;
    int b = pg >> 8;
    int ind = inds[pg];
    ind = ind < 0 ? 0 : (ind >= NN ? NN - 1 : ind);
    if (tid < SSAMP) sBuf[tid] = 0;
    size_t xb = (size_t)b * NN * 3;
    const f3v* Pts = (const f3v*)((const float*)xyz + xb);
    float cx, cy, cz;
    if (f32f) {
        f3v c = Pts[ind];
        cx = c.x; cy = c.y; cz = c.z;
    } else {
        cx = b2f(((const u16*)xyz)[xb + (size_t)ind * 3 + 0]);
        cy = b2f(((const u16*)xyz)[xb + (size_t)ind * 3 + 1]);
        cz = b2f(((const u16*)xyz)[xb + (size_t)ind * 3 + 2]);
    }
    float hx = 0.5f * ldf(bsize, pg * 3 + 0, f32f);
    float hy = 0.5f * ldf(bsize, pg * 3 + 1, f32f);
    float hz = 0.5f * ldf(bsize, pg * 3 + 2, f32f);
    int cnt = 0, par = 0;
    const unsigned long long lmask = (1ull << lane) - 1ull;
    for (int base = 0; base < NN; base += 1024, par ^= 4) {
        int nb = base + w * 256 + lane;
        int nn[4];
        float px[4], py[4], pz[4];
        #pragma unroll
        for (int u = 0; u < 4; u++) {
            int n = nb + u * 64;
            nn[u] = n;
            int nc = n < NN ? n : NN - 1;
            if (f32f) {
                f3v v = Pts[nc];
                px[u] = v.x; py[u] = v.y; pz[u] = v.z;
            } else {
                size_t a = xb + (size_t)nc * 3;
                px[u] = b2f(((const u16*)xyz)[a]);
                py[u] = b2f(((const u16*)xyz)[a + 1]);
                pz[u] = b2f(((const u16*)xyz)[a + 2]);
            }
        }
        bool isin[4];
        unsigned long long m[4];
        int pc[4];
        int tw = 0;
        #pragma unroll
        for (int u = 0; u < 4; u++) {
            bool in_ = (nn[u] < NN) &&
                       (fabsf(px[u] - cx) <= hx) &&
                       (fabsf(py[u] - cy) <= hy) &&
                       (fabsf(pz[u] - cz) <= hz);
            isin[u] = in_;
            m[u] = __ballot(in_);
            pc[u] = (int)__popcll(m[u]);
            tw += pc[u];
        }
        if (lane == 0) wcnt[par + w] = tw;
        __syncthreads();
        int w0 = wcnt[par + 0], w1 = wcnt[par + 1], w2 = wcnt[par + 2], w3 = wcnt[par + 3];
        int total = w0 + w1 + w2 + w3;
        int prior = cnt;
        if (w >= 1) prior += w0;
        if (w >= 2) prior += w1;
        if (w >= 3) prior += w2;
        #pragma unroll
        for (int u = 0; u < 4; u++) {
            int pos = prior + (int)__popcll(m[u] & lmask);
            if (isin[u] && pos < SSAMP) sBuf[pos] = nn[u];
            prior += pc[u];
        }
        cnt += total;                    // uniform across block -> uniform break
        if (cnt >= SSAMP) break;
    }
    __syncthreads();                     // order sBuf writes before final reads
    int ccap = cnt < SSAMP ? cnt : SSAMP;
    if (ccap < 1) ccap = 1;
    if (tid < SSAMP) sidx[pg * SSAMP + tid] = sBuf[tid % ccap];
    if (tid < 3) {
        float cv = tid == 0 ? cx : (tid == 1 ? cy : cz);
        outXyz[pg * 3 + tid] = cv;
        cenW[pg * 3 + tid] = cv;
    }
    if (tid == 0) outInds[pg] = rnd_bf((float)ind);
}

// ---------------- gather + 3-layer MFMA MLP + maxpool (raw max -> nfF) -------
__device__ __forceinline__ void mlp1_body(int f32f,
        const u16* __restrict__ featT, const void* __restrict__ feat,
        int pbase, int tier,
        const void* __restrict__ xyz, const int* __restrict__ sidx,
        const float* __restrict__ cenW,
        const u16* __restrict__ W0p, const u16* __restrict__ W1p,
        const u16* __restrict__ W2p, const float* __restrict__ biasF,
        u16* __restrict__ nfB, float* __restrict__ nfF,
        int tid, u16* gA, int* nrowS, float* centS) {
    int b = pbase >> 8;
    if (tid < 64) {
        int n = sidx[pbase * SSAMP + tid];
        nrowS[tid] = n < 0 ? 0 : (n >= NN ? NN - 1 : n);
    }
    if (tid < 6) centS[tid] = cenW[pbase * 3 + tid];
    for (int e = tid; e < 64 * 32; e += 256) {
        int row = e >> 5, c2 = e & 31;
        if (c2 >= 8 && c2 < 28)
            *(u32*)&gA[row * 296 + 256 + (c2 - 8) * 2] = 0u;
    }
    __syncthreads();
    if (tier >= 1) {
        size_t rowBase = (tier == 2) ? ((size_t)b * NN) : 0;
        for (int e = tid; e < 64 * 32; e += 256) {
            int row = e >> 5, seg = e & 31;
            int n = nrowS[row];
            uint4 v = *(const uint4*)(featT + (rowBase + n) * CC + seg * 8);
            *(uint4*)&gA[row * 296 + seg * 8] = v;
        }
    } else {
        int row = tid & 63;
        int n = nrowS[row];
        const size_t fb = (size_t)b * CC * NN;
        int cbase = tid >> 6;
        for (int it = 0; it < 64; it++) {
            int cch = it * 4 + cbase;
            gA[row * 296 + cch] = ldw(feat, fb + (size_t)cch * NN + n, f32f);
        }
    }
    if (tid < 64) {
        int row = tid, q = row >> 5;
        int n = nrowS[row];
        size_t a = ((size_t)b * NN + n) * 3;
        for (int d = 0; d < 3; d++) {
            float gv = ldf(xyz, a + d, f32f) - centS[q * 3 + d];
            gA[row * 296 + 256 + d] = f2b(gv);
        }
    }
    __syncthreads();

    int lane = tid & 63, w = tid >> 6;
    int c15 = lane & 15, kq = lane >> 4;
    f32x4 acc[4][2];

    // ---- layer 1: K=288 ----
    for (int mt = 0; mt < 4; mt++) for (int j = 0; j < 2; j++) acc[mt][j] = fz4();
    for (int ks = 0; ks < 9; ks++) {
        int k0 = ks * 32 + kq * 8;
        short8 af[4];
        for (int mt = 0; mt < 4; mt++)
            af[mt] = *(const short8*)&gA[(mt * 16 + c15) * 296 + k0];
        for (int j = 0; j < 2; j++) {
            int col = w * 32 + j * 16 + c15;
            short8 bf = *(const short8*)(W0p + col * 288 + k0);
            for (int mt = 0; mt < 4; mt++)
                acc[mt][j] = __builtin_amdgcn_mfma_f32_16x16x32_bf16(af[mt], bf, acc[mt][j], 0, 0, 0);
        }
    }
    __syncthreads();                 // gA reads complete before h1s aliases it
    u16* h1s = gA;                   // [0, 8704) u16
    u16* h2s = gA + 8704;            // [8704, 17408) u16
    for (int j = 0; j < 2; j++) {
        int col = w * 32 + j * 16 + c15;
        float bias = biasF[col];
        for (int mt = 0; mt < 4; mt++)
            for (int r = 0; r < 4; r++) {
                float v = acc[mt][j][r] + bias;
                v = v > 0.f ? v : 0.f;
                h1s[(mt * 16 + kq * 4 + r) * 136 + col] = f2b(v);
            }
    }
    __syncthreads();

    // ---- layer 2: K=128 ----
    for (int mt = 0; mt < 4; mt++) for (int j = 0; j < 2; j++) acc[mt][j] = fz4();
    for (int ks = 0; ks < 4; ks++) {
        int k0 = ks * 32 + kq * 8;
        short8 af[4];
        for (int mt = 0; mt < 4; mt++)
            af[mt] = *(const short8*)&h1s[(mt * 16 + c15) * 136 + k0];
        for (int j = 0; j < 2; j++) {
            int col = w * 32 + j * 16 + c15;
            short8 bf = *(const short8*)(W1p + col * 128 + k0);
            for (int mt = 0; mt < 4; mt++)
                acc[mt][j] = __builtin_amdgcn_mfma_f32_16x16x32_bf16(af[mt], bf, acc[mt][j], 0, 0, 0);
        }
    }
    __syncthreads();
    for (int j = 0; j < 2; j++) {
        int col = w * 32 + j * 16 + c15;
        float bias = biasF[128 + col];
        for (int mt = 0; mt < 4; mt++)
            for (int r = 0; r < 4; r++) {
                float v = acc[mt][j][r] + bias;
                v = v > 0.f ? v : 0.f;
                h2s[(mt * 16 + kq * 4 + r) * 136 + col] = f2b(v);
            }
    }
    __syncthreads();

    // ---- layer 3: K=128 + maxpool -> nfB (bf16) + nfF (f32, outNF layout) ----
    for (int mt = 0; mt < 4; mt++) for (int j = 0; j < 2; j++) acc[mt][j] = fz4();
    for (int ks = 0; ks < 4; ks++) {
        int k0 = ks * 32 + kq * 8;
        short8 af[4];
        for (int mt = 0; mt < 4; mt++)
            af[mt] = *(const short8*)&h2s[(mt * 16 + c15) * 136 + k0];
        for (int j = 0; j < 2; j++) {
            int col = w * 32 + j * 16 + c15;
            short8 bf = *(const short8*)(W2p + col * 128 + k0);
            for (int mt = 0; mt < 4; mt++)
                acc[mt][j] = __builtin_amdgcn_mfma_f32_16x16x32_bf16(af[mt], bf, acc[mt][j], 0, 0, 0);
        }
    }
    int pA = pbase & 255, pB = (pbase + 1) & 255;
    for (int j = 0; j < 2; j++) {
        int col = w * 32 + j * 16 + c15;
        float bias = biasF[256 + col];
        float mA = 0.f, mB = 0.f;
        for (int mt = 0; mt < 2; mt++)
            for (int r = 0; r < 4; r++) {
                float v = acc[mt][j][r] + bias; v = v > 0.f ? v : 0.f;
                mA = fmaxf(mA, v);
            }
        for (int mt = 2; mt < 4; mt++)
            for (int r = 0; r < 4; r++) {
                float v = acc[mt][j][r] + bias; v = v > 0.f ? v : 0.f;
                mB = fmaxf(mB, v);
            }
        mA = fmaxf(mA, __shfl_xor(mA, 16)); mA = fmaxf(mA, __shfl_xor(mA, 32));
        mB = fmaxf(mB, __shfl_xor(mB, 16)); mB = fmaxf(mB, __shfl_xor(mB, 32));
        if (lane < 16) {
            nfB[(size_t)(pbase + 0) * 128 + col] = f2b(mA);
            nfB[(size_t)(pbase + 1) * 128 + col] = f2b(mB);
            nfF[((size_t)b * 128 + col) * 256 + pA] = mA;
            nfF[((size_t)b * 128 + col) * 256 + pB] = mB;
        }
    }
}

// ---------------- K1 mega-front: interleaved sample/transpose | repack | lin1 -
// Sampler blocks (latency-bound) are interleaved 1:6 with transpose blocks
// (BW-bound) via stride-7 so both phases run concurrently on all XCDs
// (7 coprime with the 8-XCD round-robin).
__global__ __launch_bounds__(256) void k_front(
        const void* __restrict__ xyz, const void* __restrict__ feat,
        const void* __restrict__ bsize, const int* __restrict__ inds,
        const void* __restrict__ ts,
        const void* mw0, const void* mw1, const void* mw2,
        const void* lw0, const void* lw1, const void* lw2,
        const void* mb0, const void* mb1, const void* mb2,
        const void* lb0, const void* lb1, const void* lb2,
        const void* tw0, const void* tb0,
        const void* tlw0, const void* tlb0,
        u16* __restrict__ featT, int nTrans,
        int* __restrict__ sidx, float* __restrict__ cenW,
        float* __restrict__ outXyz, float* __restrict__ outInds,
        u16* __restrict__ W0p, u16* __restrict__ W1p, u16* __restrict__ W2p,
        u16* __restrict__ L0p, u16* __restrict__ L1p, u16* __restrict__ L2p,
        float* __restrict__ biasF, float* __restrict__ h0W, float* __restrict__ g0W) {
    __shared__ __align__(16) char smem[8448];
    int tid = threadIdx.x;
    int f32f = detect_f32d(xyz);
    unsigned bx = blockIdx.x;
    if (nTrans > 0) {
        const unsigned NI = 7u * 2048u;     // interleave region
        if (bx < NI) {
            if (bx % 7u == 0u) {
                sample_body(f32f, xyz, bsize, inds, sidx, cenW, outXyz, outInds,
                            (int)(bx / 7u), tid, (int*)smem, (int*)(smem + 128));
            } else {
                int t = (int)(bx - bx / 7u - 1u);
                if (t < nTrans)
                    transpose_body(f32f, feat, featT, t % 313, (t / 313) & 3, t / 1252,
                                   0, tid, (u16(*)[66])smem);
            }
        } else if (bx < NI + 949u) {
            repack_body(f32f, (int)(bx - NI), tid, mw0, mw1, mw2, lw0, lw1, lw2,
                        mb0, mb1, mb2, lb0, lb1, lb2, W0p, W1p, W2p, L0p, L1p, L2p, biasF);
        } else if (bx < NI + 1077u) {
            lin_body<1, 0>(f32f, ts, tw0, tb0, h0W, 128, 512, (int)(bx - NI - 949u), tid, (float*)smem);
        } else {
            lin_body<1, 1>(f32f, ts, tlw0, tlb0, g0W, 256, 1024, (int)(bx - NI - 1077u), tid, (float*)smem);
        }
    } else {
        if (bx < 2048u) {
            sample_body(f32f, xyz, bsize, inds, sidx, cenW, outXyz, outInds,
                        (int)bx, tid, (int*)smem, (int*)(smem + 128));
        } else if (bx < 2997u) {
            repack_body(f32f, (int)(bx - 2048u), tid, mw0, mw1, mw2, lw0, lw1, lw2,
                        mb0, mb1, mb2, lb0, lb1, lb2, W0p, W1p, W2p, L0p, L1p, L2p, biasF);
        } else if (bx < 3125u) {
            lin_body<1, 0>(f32f, ts, tw0, tb0, h0W, 128, 512, (int)(bx - 2997u), tid, (float*)smem);
        } else {
            lin_body<1, 1>(f32f, ts, tlw0, tlb0, g0W, 256, 1024, (int)(bx - 3125u), tid, (float*)smem);
        }
    }
}

// ---------------- K2: mlp1 + layer-2 of both time-MLP chains -----------------
__global__ __launch_bounds__(256) void k_mid(int nMlp, int blockOff, int tier,
        const u16* __restrict__ featT, const void* __restrict__ feat,
        const void* __restrict__ xyz, const int* __restrict__ sidx,
        const float* __restrict__ cenW,
        const u16* __restrict__ W0p, const u16* __restrict__ W1p,
        const u16* __restrict__ W2p, const float* __restrict__ biasF,
        u16* __restrict__ nfB, float* __restrict__ nfF,
        const void* tw1, const void* tb1, const void* tlw1, const void* tlb1,
        const float* __restrict__ h0W, const float* __restrict__ g0W,
        float* __restrict__ tembW, float* __restrict__ temblW) {
    __shared__ __align__(16) char smem[38176];
    int tid = threadIdx.x;
    int f32f = detect_f32d(xyz);
    int bx = (int)blockIdx.x;
    if (bx < nMlp) {
        mlp1_body(f32f, featT, feat, (bx + blockOff) * 2, tier, xyz, sidx, cenW,
                  W0p, W1p, W2p, biasF, nfB, nfF, tid,
                  (u16*)smem, (int*)(smem + 37888), (float*)(smem + 38144));
    } else {
        int lb = bx - nMlp;
        float* xs = (float*)smem;
        if (lb < 128) lin_body<2, 2>(f32f, h0W, tw1, tb1, tembW, 512, 512, lb, tid, xs);
        else lin_body<2, 2>(f32f, g0W, tlw1, tlb1, temblW, 1024, 1024, lb - 128, tid, xs);
    }
}

// ---------------- K3: layer-3 of both time-MLP chains ------------------------
__global__ __launch_bounds__(256) void k_lin3(const void* __restrict__ xyz,
        const void* bw, const void* bb, const void* blw, const void* blb,
        const float* __restrict__ tembW, const float* __restrict__ temblW,
        float* __restrict__ ssW, float* __restrict__ sslW) {
    __shared__ float xs[8 * 1024];
    int tid = threadIdx.x;
    int f32f = detect_f32d(xyz);
    unsigned bx = blockIdx.x;
    if (bx < 64u) lin_body<0, 2>(f32f, tembW, bw, bb, ssW, 512, 256, (int)bx, tid, xs);
    else lin_body<0, 2>(f32f, temblW, blw, blb, sslW, 1024, 512, (int)(bx - 64u), tid, xs);
}

// ---------------- standalone transpose (tier-1 path) -------------------------
__global__ __launch_bounds__(256) void k_transpose(const void* __restrict__ xyz,
                                                   const void* __restrict__ feat,
                                                   u16* __restrict__ featT, int b0) {
    __shared__ u16 tile[64][66];
    int f32f = detect_f32d(xyz);
    transpose_body(f32f, feat, featT, blockIdx.x, blockIdx.y, blockIdx.z, b0,
                   threadIdx.x, tile);
}

// ---------------- K4: label MFMA MLP + FiLM | NF FiLM ------------------------
__global__ __launch_bounds__(256) void k_tail(const void* __restrict__ xyz,
        const void* __restrict__ blabel,
        const u16* __restrict__ nfB, const u16* __restrict__ L0p,
        const u16* __restrict__ L1p, const u16* __restrict__ L2p,
        const float* __restrict__ biasF, const float* __restrict__ sslW,
        const float* __restrict__ ssW, const float* __restrict__ nfF,
        float* __restrict__ outLF, float* __restrict__ outNF) {
    __shared__ u16 liS[16 * 168];
    __shared__ u16 h1L[16 * 264];
    __shared__ u16 h2L[16 * 264];
    int f32f = detect_f32d(xyz);
    int tid = threadIdx.x;
    unsigned bxu = blockIdx.x;
    if (bxu >= 128u) {
        // NF FiLM: outNF = nfF * (scale+1) + shift  (coalesced, p fastest)
        int base = (int)(bxu - 128u) * 4096;
        #pragma unroll
        for (int i = 0; i < 16; i++) {
            int idx = base + i * 256 + tid;
            int p = idx & 255;
            int cb = idx >> 8;
            int b = cb >> 7;
            float sc = ssW[b * 256 + (p & 127)] + 1.f;
            float sh = ssW[b * 256 + 128 + (p & 127)];
            outNF[idx] = nfF[idx] * sc + sh;
        }
        return;
    }
    int pbase = (int)bxu * 16;
    for (int e = tid; e < 16 * 160; e += 256) {
        int row = e / 160, c = e % 160;
        int pg = pbase + row;
        u16 v = 0;
        if (c < 18) v = ldw(blabel, pg * 18 + c, f32f);
        else if (c < 146) v = nfB[(size_t)pg * 128 + (c - 18)];
        liS[row * 168 + c] = v;
    }
    __syncthreads();
    int lane = tid & 63, w = tid >> 6;
    int c15 = lane & 15, kq = lane >> 4;
    f32x4 acc[4];

    // layer 1: K=160
    for (int j = 0; j < 4; j++) acc[j] = fz4();
    for (int ks = 0; ks < 5; ks++) {
        int k0 = ks * 32 + kq * 8;
        short8 af = *(const short8*)&liS[c15 * 168 + k0];
        for (int j = 0; j < 4; j++) {
            int col = w * 64 + j * 16 + c15;
            short8 bf = *(const short8*)(L0p + col * 160 + k0);
            acc[j] = __builtin_amdgcn_mfma_f32_16x16x32_bf16(af, bf, acc[j], 0, 0, 0);
        }
    }
    for (int j = 0; j < 4; j++) {
        int col = w * 64 + j * 16 + c15;
        float bias = biasF[384 + col];
        for (int r = 0; r < 4; r++) {
            float v = acc[j][r] + bias; v = v > 0.f ? v : 0.f;
            h1L[(kq * 4 + r) * 264 + col] = f2b(v);
        }
    }
    __syncthreads();

    // layer 2: K=256
    for (int j = 0; j < 4; j++) acc[j] = fz4();
    for (int ks = 0; ks < 8; ks++) {
        int k0 = ks * 32 + kq * 8;
        short8 af = *(const short8*)&h1L[c15 * 264 + k0];
        for (int j = 0; j < 4; j++) {
            int col = w * 64 + j * 16 + c15;
            short8 bf = *(const short8*)(L1p + col * 256 + k0);
            acc[j] = __builtin_amdgcn_mfma_f32_16x16x32_bf16(af, bf, acc[j], 0, 0, 0);
        }
    }
    for (int j = 0; j < 4; j++) {
        int col = w * 64 + j * 16 + c15;
        float bias = biasF[640 + col];
        for (int r = 0; r < 4; r++) {
            float v = acc[j][r] + bias; v = v > 0.f ? v : 0.f;
            h2L[(kq * 4 + r) * 264 + col] = f2b(v);
        }
    }
    __syncthreads();

    // layer 3: K=256 + fused FiLM -> outLF (f32)
    for (int j = 0; j < 4; j++) acc[j] = fz4();
    for (int ks = 0; ks < 8; ks++) {
        int k0 = ks * 32 + kq * 8;
        short8 af = *(const short8*)&h2L[c15 * 264 + k0];
        for (int j = 0; j < 4; j++) {
            int col = w * 64 + j * 16 + c15;
            short8 bf = *(const short8*)(L2p + col * 256 + k0);
            acc[j] = __builtin_amdgcn_mfma_f32_16x16x32_bf16(af, bf, acc[j], 0, 0, 0);
        }
    }
    for (int j = 0; j < 4; j++) {
        int col = w * 64 + j * 16 + c15;
        float bias = biasF[896 + col];
        for (int r = 0; r < 4; r++) {
            int pr = pbase + kq * 4 + r;
            int bb2 = pr >> 8, p = pr & 255;
            float v = acc[j][r] + bias; v = v > 0.f ? v : 0.f;
            float sc = sslW[bb2 * 512 + p] + 1.f;
            float sh = sslW[bb2 * 512 + 256 + p];
            outLF[((size_t)bb2 * 256 + col) * 256 + p] = v * sc + sh;
        }
    }
}

extern "C" void kernel_launch(void* const* d_in, const int* in_sizes, int n_in,
                              void* d_out, int out_size, void* d_ws, size_t ws_size,
                              hipStream_t stream) {
    const void* xyz    = d_in[0];
    const void* feat   = d_in[1];
    const void* bsize  = d_in[2];
    const void* blabel = d_in[3];
    const void* ts     = d_in[4];
    const int* inds    = (const int*)d_in[5];
    const void* mw0 = d_in[6];  const void* mb0 = d_in[7];
    const void* mw1 = d_in[8];  const void* mb1 = d_in[9];
    const void* mw2 = d_in[10]; const void* mb2 = d_in[11];
    const void* lw0 = d_in[12]; const void* lb0 = d_in[13];
    const void* lw1 = d_in[14]; const void* lb1 = d_in[15];
    const void* lw2 = d_in[16]; const void* lb2 = d_in[17];
    const void* tw0 = d_in[18]; const void* tb0 = d_in[19];
    const void* tw1 = d_in[20]; const void* tb1 = d_in[21];
    const void* bw  = d_in[22]; const void* bb  = d_in[23];
    const void* tlw0 = d_in[24]; const void* tlb0 = d_in[25];
    const void* tlw1 = d_in[26]; const void* tlb1 = d_in[27];
    const void* blw  = d_in[28]; const void* blb  = d_in[29];

    float* out = (float*)d_out;
    float* outXyz  = out;
    float* outNF   = out + 6144;
    float* outLF   = out + 268288;
    float* outInds = out + 792576;

    char* ws = (char*)d_ws;
    u16*   W0p   = (u16*)(ws + 64);
    u16*   W1p   = (u16*)(ws + 73792);
    u16*   W2p   = (u16*)(ws + 106560);
    u16*   L0p   = (u16*)(ws + 139328);
    u16*   L1p   = (u16*)(ws + 221248);
    u16*   L2p   = (u16*)(ws + 352320);
    float* biasF = (float*)(ws + 483392);
    float* ssW   = (float*)(ws + 488000);
    float* sslW  = (float*)(ws + 496192);
    float* cenW  = (float*)(ws + 512576);
    int*   sidx  = (int*)(ws + 537152);
    u16*   nfB   = (u16*)(ws + 799296);      // 524,288
    float* h0W   = (float*)(ws + 1323584);   //  16,384
    float* tembW = (float*)(ws + 1339968);   //  16,384
    float* g0W   = (float*)(ws + 1356352);   //  32,768
    float* temblW= (float*)(ws + 1389120);   //  32,768
    float* nfF   = (float*)(ws + 1421888);   //  1,048,576
    u16*   featT = (u16*)(ws + 2470464);     //  tier A: 81,920,000 / tier B: 10,240,000
    const size_t NEED_A = 2470464ull + 81920000ull;
    const size_t NEED_B = 2470464ull + 10240000ull;
    int tier = (ws_size >= NEED_A) ? 2 : ((ws_size >= NEED_B) ? 1 : 0);

    int nTrans = (tier == 2) ? 10016 : 0;
    unsigned gFront = (nTrans > 0) ? (7u * 2048u + 949u + 384u)
                                   : (2048u + 949u + 384u);
    k_front<<<dim3(gFront), dim3(256), 0, stream>>>(
        xyz, feat, bsize, inds, ts,
        mw0, mw1, mw2, lw0, lw1, lw2,
        mb0, mb1, mb2, lb0, lb1, lb2,
        tw0, tb0, tlw0, tlb0,
        featT, nTrans, sidx, cenW, outXyz, outInds,
        W0p, W1p, W2p, L0p, L1p, L2p, biasF, h0W, g0W);

    if (tier == 2) {
        k_mid<<<dim3(1024 + 384), dim3(256), 0, stream>>>(1024, 0, 2,
            featT, feat, xyz, sidx, cenW, W0p, W1p, W2p, biasF, nfB, nfF,
            tw1, tb1, tlw1, tlb1, h0W, g0W, tembW, temblW);
    } else if (tier == 1) {
        for (int b = 0; b < BB; b++) {
            k_transpose<<<dim3(313, 4, 1), dim3(256), 0, stream>>>(xyz, feat, featT, b);
            k_mid<<<dim3(128), dim3(256), 0, stream>>>(128, b * 128, 1,
                featT, feat, xyz, sidx, cenW, W0p, W1p, W2p, biasF, nfB, nfF,
                tw1, tb1, tlw1, tlb1, h0W, g0W, tembW, temblW);
        }
        k_mid<<<dim3(384), dim3(256), 0, stream>>>(0, 0, 1,
            featT, feat, xyz, sidx, cenW, W0p, W1p, W2p, biasF, nfB, nfF,
            tw1, tb1, tlw1, tlb1, h0W, g0W, tembW, temblW);
    } else {
        k_mid<<<dim3(1024 + 384), dim3(256), 0, stream>>>(1024, 0, 0,
            featT, feat, xyz, sidx, cenW, W0p, W1p, W2p, biasF, nfB, nfF,
            tw1, tb1, tlw1, tlb1, h0W, g0W, tembW, temblW);
    }

    k_lin3<<<dim3(192), dim3(256), 0, stream>>>(xyz, bw, bb, blw, blb,
                                                tembW, temblW, ssW, sslW);

    k_tail<<<dim3(128 + 64), dim3(256), 0, stream>>>(xyz, blabel, nfB,
        L0p, L1p, L2p, biasF, sslW, ssW, nfF, outLF, outNF);
}